// Round 1
// baseline (725.972 us; speedup 1.0000x reference)
//
#include <hip/hip_runtime.h>
#include <cmath>

#define NHD 4
#define NPD 4
#define C_DIM 256
#define H_DIM 128
#define W_DIM 128
#define N_DIM (H_DIM*W_DIM)   // 16384
#define B_DIM 2
#define LN_EPSF 1e-5f

// ---------------- K1: LN over C. input x (B,C,N) -> q (B,N,C)
__global__ __launch_bounds__(256) void k_ln1(const float* __restrict__ x,
                    const float* __restrict__ g, const float* __restrict__ bta,
                    float* __restrict__ q) {
  __shared__ float tile[256*33];   // [c][n] padded
  __shared__ float psum[256], psq[256];
  __shared__ float rmean[32], rstd[32];
  int t = threadIdx.x;
  int blk = blockIdx.x;          // b*512 + ntile
  int b = blk >> 9;
  int n0 = (blk & 511) * 32;
  int nl = t & 31, cr = t >> 5;
  #pragma unroll 4
  for (int i = 0; i < 32; ++i) {
    int c = i*8 + cr;
    tile[c*33 + nl] = x[((size_t)(b*C_DIM + c))*N_DIM + n0 + nl];
  }
  __syncthreads();
  {
    int n = t & 31, j = t >> 5;
    float s = 0.f, s2 = 0.f;
    #pragma unroll 8
    for (int i = 0; i < 32; ++i) {
      float v = tile[(j*32+i)*33 + n];
      s += v; s2 += v*v;
    }
    psum[j*32+n] = s; psq[j*32+n] = s2;
  }
  __syncthreads();
  if (t < 32) {
    float s=0.f, s2=0.f;
    for (int j=0;j<8;++j){ s += psum[j*32+t]; s2 += psq[j*32+t]; }
    float m = s * (1.f/256.f);
    float var = s2 * (1.f/256.f) - m*m;
    rmean[t] = m; rstd[t] = rsqrtf(var + LN_EPSF);
  }
  __syncthreads();
  float gt = g[t], bt = bta[t];
  #pragma unroll 4
  for (int i = 0; i < 32; ++i) {
    float v = tile[t*33 + i];
    q[((size_t)(b*N_DIM + n0 + i))*C_DIM + t] = (v - rmean[i]) * rstd[i] * gt + bt;
  }
}

// ---------------- K2: value = q @ W_val^T + b_val.  A (32768,256), W (256,256) row-major
__global__ __launch_bounds__(256) void k_gemm_val(const float* __restrict__ A,
                    const float* __restrict__ Wm,
                    const float* __restrict__ bias,
                    float* __restrict__ out) {
  __shared__ __align__(16) float As[16*68];
  __shared__ __align__(16) float Bs[16*68];
  int t = threadIdx.x;
  int o0 = blockIdx.x * 64;
  int m0 = blockIdx.y * 64;
  int tx = t & 15, ty = t >> 4;
  float acc[4][4] = {};
  int lm = t >> 2;
  int lk = (t & 3) * 4;
  for (int k0 = 0; k0 < 256; k0 += 16) {
    float4 av = *(const float4*)&A[(size_t)(m0 + lm)*256 + k0 + lk];
    float4 bv = *(const float4*)&Wm[(size_t)(o0 + lm)*256 + k0 + lk];
    As[(lk+0)*68+lm]=av.x; As[(lk+1)*68+lm]=av.y; As[(lk+2)*68+lm]=av.z; As[(lk+3)*68+lm]=av.w;
    Bs[(lk+0)*68+lm]=bv.x; Bs[(lk+1)*68+lm]=bv.y; Bs[(lk+2)*68+lm]=bv.z; Bs[(lk+3)*68+lm]=bv.w;
    __syncthreads();
    #pragma unroll
    for (int kk = 0; kk < 16; ++kk) {
      float4 a = *(const float4*)&As[kk*68 + ty*4];
      float4 bq = *(const float4*)&Bs[kk*68 + tx*4];
      float avr[4] = {a.x,a.y,a.z,a.w};
      float bvr[4] = {bq.x,bq.y,bq.z,bq.w};
      #pragma unroll
      for (int i=0;i<4;++i)
        #pragma unroll
        for (int j=0;j<4;++j) acc[i][j] += avr[i]*bvr[j];
    }
    __syncthreads();
  }
  #pragma unroll
  for (int i=0;i<4;++i){
    float4 r;
    r.x = acc[i][0] + bias[o0+tx*4+0];
    r.y = acc[i][1] + bias[o0+tx*4+1];
    r.z = acc[i][2] + bias[o0+tx*4+2];
    r.w = acc[i][3] + bias[o0+tx*4+3];
    *(float4*)&out[(size_t)(m0 + ty*4 + i)*256 + o0 + tx*4] = r;
  }
}

// ---------------- K3: off/attn GEMM (48 outputs) + softmax over NP
__global__ __launch_bounds__(256) void k_offattn(const float* __restrict__ q,
      const float* __restrict__ Woff, const float* __restrict__ boff,
      const float* __restrict__ Wattn, const float* __restrict__ battn,
      float* __restrict__ off, float* __restrict__ aw) {
  __shared__ float qc[32*65];
  __shared__ float wc[48*65];
  __shared__ float res[32*48];
  int t = threadIdx.x;
  int blk = blockIdx.x; int b = blk >> 9; int n0 = (blk & 511)*32;
  int n = t & 31, og = t >> 5;
  float acc[6] = {};
  for (int k0 = 0; k0 < 256; k0 += 64) {
    #pragma unroll
    for (int r = 0; r < 2; ++r) {
      int e = t + 256*r; int rn = e >> 4; int c4 = (e & 15)*4;
      float4 v = *(const float4*)&q[(size_t)(b*N_DIM + n0 + rn)*256 + k0 + c4];
      qc[rn*65+c4+0]=v.x; qc[rn*65+c4+1]=v.y; qc[rn*65+c4+2]=v.z; qc[rn*65+c4+3]=v.w;
    }
    #pragma unroll
    for (int r = 0; r < 3; ++r) {
      int e = t + 256*r; int ro = e >> 4; int c4 = (e & 15)*4;
      const float* src = (ro < 32) ? &Woff[(size_t)ro*256 + k0 + c4]
                                   : &Wattn[(size_t)(ro-32)*256 + k0 + c4];
      float4 v = *(const float4*)src;
      wc[ro*65+c4+0]=v.x; wc[ro*65+c4+1]=v.y; wc[ro*65+c4+2]=v.z; wc[ro*65+c4+3]=v.w;
    }
    __syncthreads();
    for (int c = 0; c < 64; ++c) {
      float qv = qc[n*65 + c];
      #pragma unroll
      for (int j = 0; j < 6; ++j) acc[j] += qv * wc[(og + 8*j)*65 + c];
    }
    __syncthreads();
  }
  #pragma unroll
  for (int j = 0; j < 6; ++j) {
    int o = og + 8*j;
    float bv = (o < 32) ? boff[o] : battn[o-32];
    res[n*48 + o] = acc[j] + bv;
  }
  __syncthreads();
  #pragma unroll
  for (int r = 0; r < 4; ++r) {
    int e = t + 256*r; int rn = e >> 5; int o = e & 31;
    off[(size_t)(b*N_DIM + n0 + rn)*32 + o] = res[rn*48 + o];
  }
  if (t < 128) {
    int rn = t & 31, nh = t >> 5;
    float l0 = res[rn*48 + 32 + nh*4 + 0];
    float l1 = res[rn*48 + 32 + nh*4 + 1];
    float l2 = res[rn*48 + 32 + nh*4 + 2];
    float l3 = res[rn*48 + 32 + nh*4 + 3];
    float m = fmaxf(fmaxf(l0,l1), fmaxf(l2,l3));
    float e0 = expf(l0-m), e1 = expf(l1-m), e2 = expf(l2-m), e3 = expf(l3-m);
    float inv = 1.f / (e0+e1+e2+e3);
    size_t base = (size_t)(b*N_DIM + n0 + rn)*16 + nh*4;
    aw[base+0]=e0*inv; aw[base+1]=e1*inv; aw[base+2]=e2*inv; aw[base+3]=e3*inv;
  }
}

// ---------------- K4: deformable bilinear sampling.  wave per (b,n,nh), lane = d
__global__ __launch_bounds__(256) void k_sample(const float* __restrict__ value, // (B,N,C)
      const float* __restrict__ off, const float* __restrict__ aw,
      float* __restrict__ attn_out) { // (B,N,C)
  int t = threadIdx.x;
  int w = t >> 6;          // wave in block
  int lane = t & 63;       // = d
  int item = blockIdx.x*4 + w;          // ((b*N+n)*4 + nh)
  int nh = item & 3;
  int bn = item >> 2;                    // b*N + n
  int b  = bn >> 14;
  int n  = bn & (N_DIM-1);
  int hc = n >> 7;
  int wc = n & 127;
  size_t ob = (size_t)bn*32 + nh*8;
  size_t ab = (size_t)bn*16 + nh*4;
  size_t vbase = (size_t)(b*N_DIM)*256 + nh*64 + lane;
  float acc = 0.f;
  #pragma unroll
  for (int p = 0; p < 4; ++p) {
    float ox = off[ob + p*2 + 0];
    float oy = off[ob + p*2 + 1];
    float a  = aw[ab + p];
    float px = (float)wc + ox;
    float py = (float)hc + oy;
    float x0f = floorf(px), y0f = floorf(py);
    float wx = px - x0f, wy = py - y0f;
    int x0 = (int)x0f, y0 = (int)y0f;
    float s = 0.f;
    #pragma unroll
    for (int cy = 0; cy < 2; ++cy) {
      #pragma unroll
      for (int cx = 0; cx < 2; ++cx) {
        int xi = x0 + cx, yi = y0 + cy;
        bool valid = (xi >= 0) & (xi < W_DIM) & (yi >= 0) & (yi < H_DIM);
        int xcl = min(max(xi,0), W_DIM-1);
        int ycl = min(max(yi,0), H_DIM-1);
        float v = value[vbase + (size_t)(ycl*W_DIM + xcl)*256];
        float wgt = (cx ? wx : 1.f-wx) * (cy ? wy : 1.f-wy);
        s += valid ? wgt*v : 0.f;
      }
    }
    acc += a * s;
  }
  attn_out[(size_t)bn*256 + nh*64 + lane] = acc;
}

// ---------------- K5: out = attn_out @ W_out^T + b_out + xf; store (B,N,C) and (B,C,N)
__global__ __launch_bounds__(256) void k_gemm_out(const float* __restrict__ A,
                    const float* __restrict__ Wm,
                    const float* __restrict__ bias,
                    const float* __restrict__ x,       // (B,C,N) residual
                    float* __restrict__ outr,          // (B,N,C)
                    float* __restrict__ outt) {        // (B,C,N) -> d_out
  __shared__ __align__(16) float As[16*68];
  __shared__ __align__(16) float Bs[16*68];
  int t = threadIdx.x;
  int o0 = blockIdx.x * 64;
  int m0 = blockIdx.y * 64;
  int tx = t & 15, ty = t >> 4;
  float acc[4][4] = {};
  int lm = t >> 2;
  int lk = (t & 3) * 4;
  for (int k0 = 0; k0 < 256; k0 += 16) {
    float4 av = *(const float4*)&A[(size_t)(m0 + lm)*256 + k0 + lk];
    float4 bv = *(const float4*)&Wm[(size_t)(o0 + lm)*256 + k0 + lk];
    As[(lk+0)*68+lm]=av.x; As[(lk+1)*68+lm]=av.y; As[(lk+2)*68+lm]=av.z; As[(lk+3)*68+lm]=av.w;
    Bs[(lk+0)*68+lm]=bv.x; Bs[(lk+1)*68+lm]=bv.y; Bs[(lk+2)*68+lm]=bv.z; Bs[(lk+3)*68+lm]=bv.w;
    __syncthreads();
    #pragma unroll
    for (int kk = 0; kk < 16; ++kk) {
      float4 a = *(const float4*)&As[kk*68 + ty*4];
      float4 bq = *(const float4*)&Bs[kk*68 + tx*4];
      float avr[4] = {a.x,a.y,a.z,a.w};
      float bvr[4] = {bq.x,bq.y,bq.z,bq.w};
      #pragma unroll
      for (int i=0;i<4;++i)
        #pragma unroll
        for (int j=0;j<4;++j) acc[i][j] += avr[i]*bvr[j];
    }
    __syncthreads();
  }
  #pragma unroll
  for (int i=0;i<4;++i){
    int m = m0 + ty*4 + i;
    int b = m >> 14;
    int n = m & (N_DIM-1);
    float4 r;
    float vals[4];
    #pragma unroll
    for (int j=0;j<4;++j) {
      int o = o0 + tx*4 + j;
      float v = acc[i][j] + bias[o] + x[((size_t)(b*256+o))*N_DIM + n];
      vals[j] = v;
      outt[((size_t)(b*256+o))*N_DIM + n] = v;
    }
    r.x=vals[0]; r.y=vals[1]; r.z=vals[2]; r.w=vals[3];
    *(float4*)&outr[(size_t)m*256 + o0 + tx*4] = r;
  }
}

// ---------------- K6: LN over C, input (B,N,C) -> y (B,C,N) transposed
__global__ __launch_bounds__(256) void k_ln2t(const float* __restrict__ in,
                    const float* __restrict__ g, const float* __restrict__ bta,
                    float* __restrict__ yt) {
  __shared__ float tile[256*33];
  __shared__ float psum[256], psq[256];
  __shared__ float rmean[32], rstd[32];
  int t = threadIdx.x;
  int blk = blockIdx.x;
  int b = blk >> 9;
  int n0 = (blk & 511) * 32;
  #pragma unroll 4
  for (int i = 0; i < 32; ++i)
    tile[t*33 + i] = in[((size_t)(b*N_DIM + n0 + i))*C_DIM + t];
  __syncthreads();
  {
    int n = t & 31, j = t >> 5;
    float s = 0.f, s2 = 0.f;
    #pragma unroll 8
    for (int i = 0; i < 32; ++i) {
      float v = tile[(j*32+i)*33 + n];
      s += v; s2 += v*v;
    }
    psum[j*32+n] = s; psq[j*32+n] = s2;
  }
  __syncthreads();
  if (t < 32) {
    float s=0.f, s2=0.f;
    for (int j=0;j<8;++j){ s += psum[j*32+t]; s2 += psq[j*32+t]; }
    float m = s * (1.f/256.f);
    float var = s2 * (1.f/256.f) - m*m;
    rmean[t] = m; rstd[t] = rsqrtf(var + LN_EPSF);
  }
  __syncthreads();
  int nl = t & 31, cr = t >> 5;
  #pragma unroll 4
  for (int i = 0; i < 32; ++i) {
    int c = i*8 + cr;
    float v = tile[c*33 + nl];
    yt[((size_t)(b*C_DIM + c))*N_DIM + n0 + nl] = (v - rmean[nl]) * rstd[nl] * g[c] + bta[c];
  }
}

// ---------------- K7: depthwise 3x3 + SiLU gate -> h (B,128,N)
__global__ __launch_bounds__(256) void k_dwconv(const float* __restrict__ yt,
     const float* __restrict__ dww, const float* __restrict__ dwb,
     float* __restrict__ hb) {
  int t = threadIdx.x;
  int blk = blockIdx.x;        // b*8192 + c*64 + ht
  int ht = blk & 63; int c = (blk >> 6) & 127; int b = blk >> 13;
  int hh = t >> 7; int ww = t & 127;
  int h = ht*2 + hh;
  const float* p1 = yt + ((size_t)(b*256 + c))*N_DIM;
  const float* p2 = yt + ((size_t)(b*256 + c + 128))*N_DIM;
  float w1[9], w2[9];
  #pragma unroll
  for (int i=0;i<9;++i){ w1[i]=dww[c*9+i]; w2[i]=dww[(c+128)*9+i]; }
  float a1 = dwb[c], a2 = dwb[c+128];
  #pragma unroll
  for (int ky=0;ky<3;++ky){
    int yy = h + ky - 1;
    if (yy < 0 || yy >= H_DIM) continue;
    #pragma unroll
    for (int kx=0;kx<3;++kx){
      int xx = ww + kx - 1;
      if (xx < 0 || xx >= W_DIM) continue;
      float v1 = p1[yy*W_DIM+xx], v2 = p2[yy*W_DIM+xx];
      a1 += w1[ky*3+kx]*v1; a2 += w2[ky*3+kx]*v2;
    }
  }
  float sig = 1.f/(1.f+expf(-a1));
  hb[((size_t)(b*128+c))*N_DIM + h*W_DIM + ww] = a1*sig*a2;
}

// ---------------- K8: final = pr_w @ h + pr_b + res (in-place on d_out)
__global__ __launch_bounds__(256) void k_prfinal(const float* __restrict__ hb, // (B,128,N)
     const float* __restrict__ prw, // (256,128)
     const float* __restrict__ prb,
     float* __restrict__ dout) {    // (B,256,N), holds res, in-place add
  __shared__ __align__(16) float As[16*68];  // [k][o]
  __shared__ __align__(16) float Bs[16*68];  // [k][n]
  int t = threadIdx.x;
  int b = blockIdx.z;
  int o0 = blockIdx.x * 64;
  int n0 = blockIdx.y * 64;
  int tx = t & 15, ty = t >> 4;
  float acc[4][4] = {};
  for (int k0 = 0; k0 < 128; k0 += 16) {
    { int lo = t >> 2, lkk = (t & 3)*4;
      float4 v = *(const float4*)&prw[(size_t)(o0+lo)*128 + k0 + lkk];
      As[(lkk+0)*68+lo]=v.x; As[(lkk+1)*68+lo]=v.y; As[(lkk+2)*68+lo]=v.z; As[(lkk+3)*68+lo]=v.w; }
    { int lkk = t >> 4; int ln4 = (t & 15)*4;
      float4 v = *(const float4*)&hb[((size_t)(b*128 + k0 + lkk))*N_DIM + n0 + ln4];
      *(float4*)&Bs[lkk*68 + ln4] = v; }
    __syncthreads();
    #pragma unroll
    for (int kk = 0; kk < 16; ++kk) {
      float4 a = *(const float4*)&As[kk*68 + ty*4];
      float4 bq = *(const float4*)&Bs[kk*68 + tx*4];
      float avr[4] = {a.x,a.y,a.z,a.w};
      float bvr[4] = {bq.x,bq.y,bq.z,bq.w};
      #pragma unroll
      for (int i=0;i<4;++i)
        #pragma unroll
        for (int j=0;j<4;++j) acc[i][j] += avr[i]*bvr[j];
    }
    __syncthreads();
  }
  #pragma unroll
  for (int i=0;i<4;++i){
    int o = o0 + ty*4 + i;
    size_t base = ((size_t)(b*256 + o))*N_DIM + n0 + tx*4;
    float4 r = *(const float4*)&dout[base];
    float pb = prb[o];
    r.x += acc[i][0] + pb;
    r.y += acc[i][1] + pb;
    r.z += acc[i][2] + pb;
    r.w += acc[i][3] + pb;
    *(float4*)&dout[base] = r;
  }
}

extern "C" void kernel_launch(void* const* d_in, const int* in_sizes, int n_in,
                              void* d_out, int out_size, void* d_ws, size_t ws_size,
                              hipStream_t stream) {
  const float* x      = (const float*)d_in[0];
  const float* norm_g = (const float*)d_in[1];
  const float* norm_b = (const float*)d_in[2];
  const float* ffn_g  = (const float*)d_in[3];
  const float* ffn_b  = (const float*)d_in[4];
  const float* W_val  = (const float*)d_in[5];
  const float* b_val  = (const float*)d_in[6];
  const float* W_off  = (const float*)d_in[7];
  const float* b_off  = (const float*)d_in[8];
  const float* W_attn = (const float*)d_in[9];
  const float* b_attn = (const float*)d_in[10];
  const float* W_out  = (const float*)d_in[11];
  const float* b_out  = (const float*)d_in[12];
  const float* dw_w   = (const float*)d_in[13];
  const float* dw_b   = (const float*)d_in[14];
  const float* pr_w   = (const float*)d_in[15];
  const float* pr_b   = (const float*)d_in[16];
  float* outp = (float*)d_out;

  char* ws = (char*)d_ws;
  const size_t MN = (size_t)B_DIM * N_DIM;          // 32768
  float* buf0 = (float*)ws;                          // q -> attn_out -> y_t
  float* buf1 = (float*)(ws + MN*256*sizeof(float)); // value -> out -> h
  float* boff = (float*)(ws + 2*MN*256*sizeof(float));
  float* baw  = (float*)(ws + 2*MN*256*sizeof(float) + MN*32*sizeof(float));

  // 1. LN1: x -> q (buf0)
  k_ln1<<<dim3(1024), dim3(256), 0, stream>>>(x, norm_g, norm_b, buf0);
  // 2. value = q @ W_val^T + b_val (buf1)
  k_gemm_val<<<dim3(4,512), dim3(256), 0, stream>>>(buf0, W_val, b_val, buf1);
  // 3. off / aw
  k_offattn<<<dim3(1024), dim3(256), 0, stream>>>(buf0, W_off, b_off, W_attn, b_attn, boff, baw);
  // 4. deformable sampling -> attn_out (buf0; q dead)
  k_sample<<<dim3(32768), dim3(256), 0, stream>>>(buf1, boff, baw, buf0);
  // 5. out = attn_out @ W_out^T + b_out + xf; row-major in buf1 (value dead), transposed in d_out
  k_gemm_out<<<dim3(4,512), dim3(256), 0, stream>>>(buf0, W_out, b_out, x, buf1, outp);
  // 6. LN2 + transpose: buf1 -> y_t (buf0)
  k_ln2t<<<dim3(1024), dim3(256), 0, stream>>>(buf1, ffn_g, ffn_b, buf0);
  // 7. depthwise conv + SiLU gate: y_t -> h (buf1; out dead)
  k_dwconv<<<dim3(16384), dim3(256), 0, stream>>>(buf0, dw_w, dw_b, buf1);
  // 8. final: d_out += pr_w @ h + pr_b  (d_out holds res)
  k_prfinal<<<dim3(4,256,2), dim3(256), 0, stream>>>(buf1, pr_w, pr_b, outp);

  (void)in_sizes; (void)n_in; (void)out_size; (void)ws_size;
}

// Round 2
// 321.221 us; speedup vs baseline: 2.2600x; 2.2600x over previous
//
#include <hip/hip_runtime.h>
#include <cmath>

#define NHD 4
#define NPD 4
#define C_DIM 256
#define H_DIM 128
#define W_DIM 128
#define N_DIM (H_DIM*W_DIM)   // 16384
#define B_DIM 2
#define LN_EPSF 1e-5f

// ---------------- K1: LN over C. input x (B,C,N) -> q (B,N,C)
__global__ __launch_bounds__(256) void k_ln1(const float* __restrict__ x,
                    const float* __restrict__ g, const float* __restrict__ bta,
                    float* __restrict__ q) {
  __shared__ float tile[256*33];   // [c][n] padded
  __shared__ float psum[256], psq[256];
  __shared__ float rmean[32], rstd[32];
  int t = threadIdx.x;
  int blk = blockIdx.x;          // b*512 + ntile
  int b = blk >> 9;
  int n0 = (blk & 511) * 32;
  int nl = t & 31, cr = t >> 5;
  #pragma unroll 4
  for (int i = 0; i < 32; ++i) {
    int c = i*8 + cr;
    tile[c*33 + nl] = x[((size_t)(b*C_DIM + c))*N_DIM + n0 + nl];
  }
  __syncthreads();
  {
    int n = t & 31, j = t >> 5;
    float s = 0.f, s2 = 0.f;
    #pragma unroll 8
    for (int i = 0; i < 32; ++i) {
      float v = tile[(j*32+i)*33 + n];
      s += v; s2 += v*v;
    }
    psum[j*32+n] = s; psq[j*32+n] = s2;
  }
  __syncthreads();
  if (t < 32) {
    float s=0.f, s2=0.f;
    for (int j=0;j<8;++j){ s += psum[j*32+t]; s2 += psq[j*32+t]; }
    float m = s * (1.f/256.f);
    float var = s2 * (1.f/256.f) - m*m;
    rmean[t] = m; rstd[t] = rsqrtf(var + LN_EPSF);
  }
  __syncthreads();
  float gt = g[t], bt = bta[t];
  #pragma unroll 4
  for (int i = 0; i < 32; ++i) {
    float v = tile[t*33 + i];
    q[((size_t)(b*N_DIM + n0 + i))*C_DIM + t] = (v - rmean[i]) * rstd[i] * gt + bt;
  }
}

// ---------------- K2: value = q @ W_val^T + b_val.  A (32768,256), W (256,256) row-major
__global__ __launch_bounds__(256) void k_gemm_val(const float* __restrict__ A,
                    const float* __restrict__ Wm,
                    const float* __restrict__ bias,
                    float* __restrict__ out) {
  __shared__ __align__(16) float As[16*68];
  __shared__ __align__(16) float Bs[16*68];
  int t = threadIdx.x;
  int o0 = blockIdx.x * 64;
  int m0 = blockIdx.y * 64;
  int tx = t & 15, ty = t >> 4;
  float acc[4][4] = {};
  int lm = t >> 2;
  int lk = (t & 3) * 4;
  for (int k0 = 0; k0 < 256; k0 += 16) {
    float4 av = *(const float4*)&A[(size_t)(m0 + lm)*256 + k0 + lk];
    float4 bv = *(const float4*)&Wm[(size_t)(o0 + lm)*256 + k0 + lk];
    As[(lk+0)*68+lm]=av.x; As[(lk+1)*68+lm]=av.y; As[(lk+2)*68+lm]=av.z; As[(lk+3)*68+lm]=av.w;
    Bs[(lk+0)*68+lm]=bv.x; Bs[(lk+1)*68+lm]=bv.y; Bs[(lk+2)*68+lm]=bv.z; Bs[(lk+3)*68+lm]=bv.w;
    __syncthreads();
    #pragma unroll
    for (int kk = 0; kk < 16; ++kk) {
      float4 a = *(const float4*)&As[kk*68 + ty*4];
      float4 bq = *(const float4*)&Bs[kk*68 + tx*4];
      float avr[4] = {a.x,a.y,a.z,a.w};
      float bvr[4] = {bq.x,bq.y,bq.z,bq.w};
      #pragma unroll
      for (int i=0;i<4;++i)
        #pragma unroll
        for (int j=0;j<4;++j) acc[i][j] += avr[i]*bvr[j];
    }
    __syncthreads();
  }
  #pragma unroll
  for (int i=0;i<4;++i){
    float4 r;
    r.x = acc[i][0] + bias[o0+tx*4+0];
    r.y = acc[i][1] + bias[o0+tx*4+1];
    r.z = acc[i][2] + bias[o0+tx*4+2];
    r.w = acc[i][3] + bias[o0+tx*4+3];
    *(float4*)&out[(size_t)(m0 + ty*4 + i)*256 + o0 + tx*4] = r;
  }
}

// ---------------- K3 (rewritten): off/attn GEMM (48 outputs) + softmax over NP
// Block: 64 rows, 256 threads. W (48x256) staged fully in LDS (broadcast reads);
// q staged in transposed 64x64 chunks (stride 65, conflict-free).
// Thread (n = t&63, og = t>>6) computes 12 outputs o = og*12+j.
__global__ __launch_bounds__(256) void k_offattn(const float* __restrict__ q,
      const float* __restrict__ Woff, const float* __restrict__ boff,
      const float* __restrict__ Wattn, const float* __restrict__ battn,
      float* __restrict__ off, float* __restrict__ aw) {
  __shared__ __align__(16) float wls[48*256];   // [o][k]
  __shared__ float qls[64*65];                  // [k][n] padded
  int t = threadIdx.x;
  int n = t & 63, og = t >> 6;
  int row0 = blockIdx.x * 64;                   // global row = b*N + n
  // stage W once: 3072 float4
  #pragma unroll
  for (int r = 0; r < 12; ++r) {
    int e = t + 256*r;                // float4 index
    int ro = e >> 6;                  // 0..47
    int c4 = (e & 63) * 4;
    const float* src = (ro < 32) ? &Woff[(size_t)ro*256 + c4]
                                 : &Wattn[(size_t)(ro-32)*256 + c4];
    *(float4*)&wls[ro*256 + c4] = *(const float4*)src;
  }
  float acc[12] = {};
  for (int k0 = 0; k0 < 256; k0 += 64) {
    __syncthreads();
    // stage q chunk transposed: [kk][row]
    #pragma unroll
    for (int r = 0; r < 4; ++r) {
      int e = t + 256*r;
      int rw = e >> 4;                // 0..63
      int c4 = (e & 15) * 4;          // 0..60
      float4 v = *(const float4*)&q[(size_t)(row0 + rw)*256 + k0 + c4];
      qls[(c4+0)*65 + rw] = v.x;
      qls[(c4+1)*65 + rw] = v.y;
      qls[(c4+2)*65 + rw] = v.z;
      qls[(c4+3)*65 + rw] = v.w;
    }
    __syncthreads();
    #pragma unroll 4
    for (int kk = 0; kk < 64; kk += 4) {
      float q0 = qls[(kk+0)*65 + n];
      float q1 = qls[(kk+1)*65 + n];
      float q2 = qls[(kk+2)*65 + n];
      float q3 = qls[(kk+3)*65 + n];
      #pragma unroll
      for (int j = 0; j < 12; ++j) {
        float4 wv = *(const float4*)&wls[(og*12+j)*256 + k0 + kk];
        acc[j] += q0*wv.x + q1*wv.y + q2*wv.z + q3*wv.w;
      }
    }
  }
  // bias + outputs
  float vals[12];
  #pragma unroll
  for (int j = 0; j < 12; ++j) {
    int o = og*12 + j;
    float bv = (o < 32) ? boff[o] : battn[o-32];
    vals[j] = acc[j] + bv;
  }
  size_t rowg = row0 + n;
  if (og < 2) {
    #pragma unroll
    for (int j = 0; j < 12; ++j) off[rowg*32 + og*12 + j] = vals[j];
  } else if (og == 2) {
    #pragma unroll
    for (int j = 0; j < 8; ++j) off[rowg*32 + 24 + j] = vals[j];
    float m = fmaxf(fmaxf(vals[8],vals[9]), fmaxf(vals[10],vals[11]));
    float e0 = expf(vals[8]-m), e1 = expf(vals[9]-m), e2 = expf(vals[10]-m), e3 = expf(vals[11]-m);
    float inv = 1.f/(e0+e1+e2+e3);
    aw[rowg*16+0]=e0*inv; aw[rowg*16+1]=e1*inv; aw[rowg*16+2]=e2*inv; aw[rowg*16+3]=e3*inv;
  } else {
    #pragma unroll
    for (int gidx = 0; gidx < 3; ++gidx) {
      float l0=vals[gidx*4+0], l1=vals[gidx*4+1], l2=vals[gidx*4+2], l3=vals[gidx*4+3];
      float m = fmaxf(fmaxf(l0,l1), fmaxf(l2,l3));
      float e0=expf(l0-m), e1=expf(l1-m), e2=expf(l2-m), e3=expf(l3-m);
      float inv = 1.f/(e0+e1+e2+e3);
      size_t base = rowg*16 + 4 + gidx*4;
      aw[base+0]=e0*inv; aw[base+1]=e1*inv; aw[base+2]=e2*inv; aw[base+3]=e3*inv;
    }
  }
}

// ---------------- K4: deformable bilinear sampling.  wave per (b,n,nh), lane = d
__global__ __launch_bounds__(256) void k_sample(const float* __restrict__ value, // (B,N,C)
      const float* __restrict__ off, const float* __restrict__ aw,
      float* __restrict__ attn_out) { // (B,N,C)
  int t = threadIdx.x;
  int w = t >> 6;          // wave in block
  int lane = t & 63;       // = d
  int item = blockIdx.x*4 + w;          // ((b*N+n)*4 + nh)
  int nh = item & 3;
  int bn = item >> 2;                    // b*N + n
  int b  = bn >> 14;
  int n  = bn & (N_DIM-1);
  int hc = n >> 7;
  int wc = n & 127;
  size_t ob = (size_t)bn*32 + nh*8;
  size_t ab = (size_t)bn*16 + nh*4;
  size_t vbase = (size_t)(b*N_DIM)*256 + nh*64 + lane;
  float acc = 0.f;
  #pragma unroll
  for (int p = 0; p < 4; ++p) {
    float ox = off[ob + p*2 + 0];
    float oy = off[ob + p*2 + 1];
    float a  = aw[ab + p];
    float px = (float)wc + ox;
    float py = (float)hc + oy;
    float x0f = floorf(px), y0f = floorf(py);
    float wx = px - x0f, wy = py - y0f;
    int x0 = (int)x0f, y0 = (int)y0f;
    float s = 0.f;
    #pragma unroll
    for (int cy = 0; cy < 2; ++cy) {
      #pragma unroll
      for (int cx = 0; cx < 2; ++cx) {
        int xi = x0 + cx, yi = y0 + cy;
        bool valid = (xi >= 0) & (xi < W_DIM) & (yi >= 0) & (yi < H_DIM);
        int xcl = min(max(xi,0), W_DIM-1);
        int ycl = min(max(yi,0), H_DIM-1);
        float v = value[vbase + (size_t)(ycl*W_DIM + xcl)*256];
        float wgt = (cx ? wx : 1.f-wx) * (cy ? wy : 1.f-wy);
        s += valid ? wgt*v : 0.f;
      }
    }
    acc += a * s;
  }
  attn_out[(size_t)bn*256 + nh*64 + lane] = acc;
}

// ---------------- K5: out = attn_out @ W_out^T + b_out + xf; store (B,N,C) and (B,C,N)
__global__ __launch_bounds__(256) void k_gemm_out(const float* __restrict__ A,
                    const float* __restrict__ Wm,
                    const float* __restrict__ bias,
                    const float* __restrict__ x,       // (B,C,N) residual
                    float* __restrict__ outr,          // (B,N,C)
                    float* __restrict__ outt) {        // (B,C,N) -> d_out
  __shared__ __align__(16) float As[16*68];
  __shared__ __align__(16) float Bs[16*68];
  int t = threadIdx.x;
  int o0 = blockIdx.x * 64;
  int m0 = blockIdx.y * 64;
  int tx = t & 15, ty = t >> 4;
  float acc[4][4] = {};
  int lm = t >> 2;
  int lk = (t & 3) * 4;
  for (int k0 = 0; k0 < 256; k0 += 16) {
    float4 av = *(const float4*)&A[(size_t)(m0 + lm)*256 + k0 + lk];
    float4 bv = *(const float4*)&Wm[(size_t)(o0 + lm)*256 + k0 + lk];
    As[(lk+0)*68+lm]=av.x; As[(lk+1)*68+lm]=av.y; As[(lk+2)*68+lm]=av.z; As[(lk+3)*68+lm]=av.w;
    Bs[(lk+0)*68+lm]=bv.x; Bs[(lk+1)*68+lm]=bv.y; Bs[(lk+2)*68+lm]=bv.z; Bs[(lk+3)*68+lm]=bv.w;
    __syncthreads();
    #pragma unroll
    for (int kk = 0; kk < 16; ++kk) {
      float4 a = *(const float4*)&As[kk*68 + ty*4];
      float4 bq = *(const float4*)&Bs[kk*68 + tx*4];
      float avr[4] = {a.x,a.y,a.z,a.w};
      float bvr[4] = {bq.x,bq.y,bq.z,bq.w};
      #pragma unroll
      for (int i=0;i<4;++i)
        #pragma unroll
        for (int j=0;j<4;++j) acc[i][j] += avr[i]*bvr[j];
    }
    __syncthreads();
  }
  #pragma unroll
  for (int i=0;i<4;++i){
    int m = m0 + ty*4 + i;
    int b = m >> 14;
    int n = m & (N_DIM-1);
    float4 r;
    float vals[4];
    #pragma unroll
    for (int j=0;j<4;++j) {
      int o = o0 + tx*4 + j;
      float v = acc[i][j] + bias[o] + x[((size_t)(b*256+o))*N_DIM + n];
      vals[j] = v;
      outt[((size_t)(b*256+o))*N_DIM + n] = v;
    }
    r.x=vals[0]; r.y=vals[1]; r.z=vals[2]; r.w=vals[3];
    *(float4*)&outr[(size_t)m*256 + o0 + tx*4] = r;
  }
}

// ---------------- K6: LN over C, input (B,N,C) -> y (B,C,N) transposed
__global__ __launch_bounds__(256) void k_ln2t(const float* __restrict__ in,
                    const float* __restrict__ g, const float* __restrict__ bta,
                    float* __restrict__ yt) {
  __shared__ float tile[256*33];
  __shared__ float psum[256], psq[256];
  __shared__ float rmean[32], rstd[32];
  int t = threadIdx.x;
  int blk = blockIdx.x;
  int b = blk >> 9;
  int n0 = (blk & 511) * 32;
  #pragma unroll 4
  for (int i = 0; i < 32; ++i)
    tile[t*33 + i] = in[((size_t)(b*N_DIM + n0 + i))*C_DIM + t];
  __syncthreads();
  {
    int n = t & 31, j = t >> 5;
    float s = 0.f, s2 = 0.f;
    #pragma unroll 8
    for (int i = 0; i < 32; ++i) {
      float v = tile[(j*32+i)*33 + n];
      s += v; s2 += v*v;
    }
    psum[j*32+n] = s; psq[j*32+n] = s2;
  }
  __syncthreads();
  if (t < 32) {
    float s=0.f, s2=0.f;
    for (int j=0;j<8;++j){ s += psum[j*32+t]; s2 += psq[j*32+t]; }
    float m = s * (1.f/256.f);
    float var = s2 * (1.f/256.f) - m*m;
    rmean[t] = m; rstd[t] = rsqrtf(var + LN_EPSF);
  }
  __syncthreads();
  int nl = t & 31, cr = t >> 5;
  #pragma unroll 4
  for (int i = 0; i < 32; ++i) {
    int c = i*8 + cr;
    float v = tile[c*33 + nl];
    yt[((size_t)(b*C_DIM + c))*N_DIM + n0 + nl] = (v - rmean[nl]) * rstd[nl] * g[c] + bta[c];
  }
}

// ---------------- K7: depthwise 3x3 + SiLU gate -> h (B,128,N)
__global__ __launch_bounds__(256) void k_dwconv(const float* __restrict__ yt,
     const float* __restrict__ dww, const float* __restrict__ dwb,
     float* __restrict__ hb) {
  int t = threadIdx.x;
  int blk = blockIdx.x;        // b*8192 + c*64 + ht
  int ht = blk & 63; int c = (blk >> 6) & 127; int b = blk >> 13;
  int hh = t >> 7; int ww = t & 127;
  int h = ht*2 + hh;
  const float* p1 = yt + ((size_t)(b*256 + c))*N_DIM;
  const float* p2 = yt + ((size_t)(b*256 + c + 128))*N_DIM;
  float w1[9], w2[9];
  #pragma unroll
  for (int i=0;i<9;++i){ w1[i]=dww[c*9+i]; w2[i]=dww[(c+128)*9+i]; }
  float a1 = dwb[c], a2 = dwb[c+128];
  #pragma unroll
  for (int ky=0;ky<3;++ky){
    int yy = h + ky - 1;
    if (yy < 0 || yy >= H_DIM) continue;
    #pragma unroll
    for (int kx=0;kx<3;++kx){
      int xx = ww + kx - 1;
      if (xx < 0 || xx >= W_DIM) continue;
      float v1 = p1[yy*W_DIM+xx], v2 = p2[yy*W_DIM+xx];
      a1 += w1[ky*3+kx]*v1; a2 += w2[ky*3+kx]*v2;
    }
  }
  float sig = 1.f/(1.f+expf(-a1));
  hb[((size_t)(b*128+c))*N_DIM + h*W_DIM + ww] = a1*sig*a2;
}

// ---------------- K8: final = pr_w @ h + pr_b + res (in-place on d_out)
__global__ __launch_bounds__(256) void k_prfinal(const float* __restrict__ hb, // (B,128,N)
     const float* __restrict__ prw, // (256,128)
     const float* __restrict__ prb,
     float* __restrict__ dout) {    // (B,256,N), holds res, in-place add
  __shared__ __align__(16) float As[16*68];  // [k][o]
  __shared__ __align__(16) float Bs[16*68];  // [k][n]
  int t = threadIdx.x;
  int b = blockIdx.z;
  int o0 = blockIdx.x * 64;
  int n0 = blockIdx.y * 64;
  int tx = t & 15, ty = t >> 4;
  float acc[4][4] = {};
  for (int k0 = 0; k0 < 128; k0 += 16) {
    { int lo = t >> 2, lkk = (t & 3)*4;
      float4 v = *(const float4*)&prw[(size_t)(o0+lo)*128 + k0 + lkk];
      As[(lkk+0)*68+lo]=v.x; As[(lkk+1)*68+lo]=v.y; As[(lkk+2)*68+lo]=v.z; As[(lkk+3)*68+lo]=v.w; }
    { int lkk = t >> 4; int ln4 = (t & 15)*4;
      float4 v = *(const float4*)&hb[((size_t)(b*128 + k0 + lkk))*N_DIM + n0 + ln4];
      *(float4*)&Bs[lkk*68 + ln4] = v; }
    __syncthreads();
    #pragma unroll
    for (int kk = 0; kk < 16; ++kk) {
      float4 a = *(const float4*)&As[kk*68 + ty*4];
      float4 bq = *(const float4*)&Bs[kk*68 + tx*4];
      float avr[4] = {a.x,a.y,a.z,a.w};
      float bvr[4] = {bq.x,bq.y,bq.z,bq.w};
      #pragma unroll
      for (int i=0;i<4;++i)
        #pragma unroll
        for (int j=0;j<4;++j) acc[i][j] += avr[i]*bvr[j];
    }
    __syncthreads();
  }
  #pragma unroll
  for (int i=0;i<4;++i){
    int o = o0 + ty*4 + i;
    size_t base = ((size_t)(b*256 + o))*N_DIM + n0 + tx*4;
    float4 r = *(const float4*)&dout[base];
    float pb = prb[o];
    r.x += acc[i][0] + pb;
    r.y += acc[i][1] + pb;
    r.z += acc[i][2] + pb;
    r.w += acc[i][3] + pb;
    *(float4*)&dout[base] = r;
  }
}

extern "C" void kernel_launch(void* const* d_in, const int* in_sizes, int n_in,
                              void* d_out, int out_size, void* d_ws, size_t ws_size,
                              hipStream_t stream) {
  const float* x      = (const float*)d_in[0];
  const float* norm_g = (const float*)d_in[1];
  const float* norm_b = (const float*)d_in[2];
  const float* ffn_g  = (const float*)d_in[3];
  const float* ffn_b  = (const float*)d_in[4];
  const float* W_val  = (const float*)d_in[5];
  const float* b_val  = (const float*)d_in[6];
  const float* W_off  = (const float*)d_in[7];
  const float* b_off  = (const float*)d_in[8];
  const float* W_attn = (const float*)d_in[9];
  const float* b_attn = (const float*)d_in[10];
  const float* W_out  = (const float*)d_in[11];
  const float* b_out  = (const float*)d_in[12];
  const float* dw_w   = (const float*)d_in[13];
  const float* dw_b   = (const float*)d_in[14];
  const float* pr_w   = (const float*)d_in[15];
  const float* pr_b   = (const float*)d_in[16];
  float* outp = (float*)d_out;

  char* ws = (char*)d_ws;
  const size_t MN = (size_t)B_DIM * N_DIM;          // 32768
  float* buf0 = (float*)ws;                          // q -> attn_out -> y_t
  float* buf1 = (float*)(ws + MN*256*sizeof(float)); // value -> out -> h
  float* boff = (float*)(ws + 2*MN*256*sizeof(float));
  float* baw  = (float*)(ws + 2*MN*256*sizeof(float) + MN*32*sizeof(float));

  // 1. LN1: x -> q (buf0)
  k_ln1<<<dim3(1024), dim3(256), 0, stream>>>(x, norm_g, norm_b, buf0);
  // 2. value = q @ W_val^T + b_val (buf1)
  k_gemm_val<<<dim3(4,512), dim3(256), 0, stream>>>(buf0, W_val, b_val, buf1);
  // 3. off / aw
  k_offattn<<<dim3(512), dim3(256), 0, stream>>>(buf0, W_off, b_off, W_attn, b_attn, boff, baw);
  // 4. deformable sampling -> attn_out (buf0; q dead)
  k_sample<<<dim3(32768), dim3(256), 0, stream>>>(buf1, boff, baw, buf0);
  // 5. out = attn_out @ W_out^T + b_out + xf; row-major in buf1 (value dead), transposed in d_out
  k_gemm_out<<<dim3(4,512), dim3(256), 0, stream>>>(buf0, W_out, b_out, x, buf1, outp);
  // 6. LN2 + transpose: buf1 -> y_t (buf0)
  k_ln2t<<<dim3(1024), dim3(256), 0, stream>>>(buf1, ffn_g, ffn_b, buf0);
  // 7. depthwise conv + SiLU gate: y_t -> h (buf1; out dead)
  k_dwconv<<<dim3(16384), dim3(256), 0, stream>>>(buf0, dw_w, dw_b, buf1);
  // 8. final: d_out += pr_w @ h + pr_b  (d_out holds res)
  k_prfinal<<<dim3(4,256,2), dim3(256), 0, stream>>>(buf1, pr_w, pr_b, outp);

  (void)in_sizes; (void)n_in; (void)out_size; (void)ws_size;
}

// Round 3
// 216.321 us; speedup vs baseline: 3.3560x; 1.4849x over previous
//
#include <hip/hip_runtime.h>
#include <cmath>

typedef unsigned short u16;
typedef __attribute__((ext_vector_type(8))) short short8v;   // 8 bf16
typedef __attribute__((ext_vector_type(4))) float f32x4;

#define C_DIM 256
#define H_DIM 128
#define W_DIM 128
#define N_DIM (H_DIM*W_DIM)   // 16384
#define B_DIM 2
#define LN_EPSF 1e-5f

__device__ __forceinline__ u16 f2b(float f) {
  unsigned u = __float_as_uint(f);
  unsigned r = (u + 0x7fffu + ((u >> 16) & 1u)) >> 16;   // RNE
  return (u16)r;
}
__device__ __forceinline__ float b2f(u16 h) {
  return __uint_as_float(((unsigned)h) << 16);
}

// ---------------- K0: f32 -> bf16 weight conversion
__global__ __launch_bounds__(256) void k_cvt(const float* __restrict__ s,
                                             u16* __restrict__ d, int n4) {
  int i = blockIdx.x*256 + threadIdx.x;
  if (i < n4) {
    float4 v = *(const float4*)&s[i*4];
    d[i*4+0]=f2b(v.x); d[i*4+1]=f2b(v.y); d[i*4+2]=f2b(v.z); d[i*4+3]=f2b(v.w);
  }
}

// ---------------- K1: LN over C. input x (B,C,N) -> q (B,N,C) bf16
__global__ __launch_bounds__(256) void k_ln1(const float* __restrict__ x,
                    const float* __restrict__ g, const float* __restrict__ bta,
                    u16* __restrict__ q) {
  __shared__ float tile[256*33];   // [c][n] padded
  __shared__ float psum[256], psq[256];
  __shared__ float rmean[32], rstd[32];
  int t = threadIdx.x;
  int blk = blockIdx.x;          // b*512 + ntile
  int b = blk >> 9;
  int n0 = (blk & 511) * 32;
  int nl = t & 31, cr = t >> 5;
  #pragma unroll 4
  for (int i = 0; i < 32; ++i) {
    int c = i*8 + cr;
    tile[c*33 + nl] = x[((size_t)(b*C_DIM + c))*N_DIM + n0 + nl];
  }
  __syncthreads();
  {
    int n = t & 31, j = t >> 5;
    float s = 0.f, s2 = 0.f;
    #pragma unroll 8
    for (int i = 0; i < 32; ++i) {
      float v = tile[(j*32+i)*33 + n];
      s += v; s2 += v*v;
    }
    psum[j*32+n] = s; psq[j*32+n] = s2;
  }
  __syncthreads();
  if (t < 32) {
    float s=0.f, s2=0.f;
    for (int j=0;j<8;++j){ s += psum[j*32+t]; s2 += psq[j*32+t]; }
    float m = s * (1.f/256.f);
    float var = s2 * (1.f/256.f) - m*m;
    rmean[t] = m; rstd[t] = rsqrtf(var + LN_EPSF);
  }
  __syncthreads();
  float gt = g[t], bt = bta[t];
  #pragma unroll 4
  for (int i = 0; i < 32; ++i) {
    float v = tile[t*33 + i];
    q[((size_t)(b*N_DIM + n0 + i))*C_DIM + t] = f2b((v - rmean[i]) * rstd[i] * gt + bt);
  }
}

// ---------------- K2: value = q @ W_val^T + b_val, bf16 MFMA, out bf16
// block: 256 thr = 4 waves; m-tile 64, full N=256 (wave w -> o in [w*64, w*64+64))
__global__ __launch_bounds__(256) void k_gemm_val_mfma(const u16* __restrict__ A,
      const u16* __restrict__ Wb, const float* __restrict__ bias,
      u16* __restrict__ out) {
  int t = threadIdx.x;
  int lane = t & 63, w = t >> 6;
  int m0 = blockIdx.x * 64;
  int l15 = lane & 15, lk = (lane >> 4) * 8;
  f32x4 acc[4][4] = {};   // [mi][oj]
  float bias_v[4];
  #pragma unroll
  for (int oj = 0; oj < 4; ++oj) bias_v[oj] = bias[w*64 + oj*16 + l15];
  #pragma unroll
  for (int k0 = 0; k0 < 256; k0 += 32) {
    short8v af[4], bf[4];
    #pragma unroll
    for (int mi = 0; mi < 4; ++mi)
      af[mi] = *(const short8v*)&A[(size_t)(m0 + mi*16 + l15)*256 + k0 + lk];
    #pragma unroll
    for (int oj = 0; oj < 4; ++oj)
      bf[oj] = *(const short8v*)&Wb[(size_t)(w*64 + oj*16 + l15)*256 + k0 + lk];
    #pragma unroll
    for (int mi = 0; mi < 4; ++mi)
      #pragma unroll
      for (int oj = 0; oj < 4; ++oj)
        acc[mi][oj] = __builtin_amdgcn_mfma_f32_16x16x32_bf16(af[mi], bf[oj], acc[mi][oj], 0,0,0);
  }
  int rbase = (lane >> 4) * 4;
  #pragma unroll
  for (int mi = 0; mi < 4; ++mi)
    #pragma unroll
    for (int oj = 0; oj < 4; ++oj)
      #pragma unroll
      for (int r = 0; r < 4; ++r) {
        int m = m0 + mi*16 + rbase + r;
        int o = w*64 + oj*16 + l15;
        out[(size_t)m*256 + o] = f2b(acc[mi][oj][r] + bias_v[oj]);
      }
}

// ---------------- K5: ao = attn_out @ W_out^T + b_out, bf16 MFMA, out f32 (B,N,C)
__global__ __launch_bounds__(256) void k_gemm_out_mfma(const u16* __restrict__ A,
      const u16* __restrict__ Wb, const float* __restrict__ bias,
      float* __restrict__ out) {
  int t = threadIdx.x;
  int lane = t & 63, w = t >> 6;
  int m0 = blockIdx.x * 64;
  int l15 = lane & 15, lk = (lane >> 4) * 8;
  f32x4 acc[4][4] = {};
  float bias_v[4];
  #pragma unroll
  for (int oj = 0; oj < 4; ++oj) bias_v[oj] = bias[w*64 + oj*16 + l15];
  #pragma unroll
  for (int k0 = 0; k0 < 256; k0 += 32) {
    short8v af[4], bf[4];
    #pragma unroll
    for (int mi = 0; mi < 4; ++mi)
      af[mi] = *(const short8v*)&A[(size_t)(m0 + mi*16 + l15)*256 + k0 + lk];
    #pragma unroll
    for (int oj = 0; oj < 4; ++oj)
      bf[oj] = *(const short8v*)&Wb[(size_t)(w*64 + oj*16 + l15)*256 + k0 + lk];
    #pragma unroll
    for (int mi = 0; mi < 4; ++mi)
      #pragma unroll
      for (int oj = 0; oj < 4; ++oj)
        acc[mi][oj] = __builtin_amdgcn_mfma_f32_16x16x32_bf16(af[mi], bf[oj], acc[mi][oj], 0,0,0);
  }
  int rbase = (lane >> 4) * 4;
  #pragma unroll
  for (int mi = 0; mi < 4; ++mi)
    #pragma unroll
    for (int oj = 0; oj < 4; ++oj)
      #pragma unroll
      for (int r = 0; r < 4; ++r) {
        int m = m0 + mi*16 + rbase + r;
        int o = w*64 + oj*16 + l15;
        out[(size_t)m*256 + o] = acc[mi][oj][r] + bias_v[oj];
      }
}

// ---------------- K3: off/attn GEMM (48 outputs) + softmax, q in bf16
__global__ __launch_bounds__(256) void k_offattn(const u16* __restrict__ q,
      const float* __restrict__ Woff, const float* __restrict__ boff,
      const float* __restrict__ Wattn, const float* __restrict__ battn,
      float* __restrict__ off, float* __restrict__ aw) {
  __shared__ __align__(16) float wls[48*256];   // [o][k]
  __shared__ float qls[64*65];                  // [k][n] padded
  int t = threadIdx.x;
  int n = t & 63, og = t >> 6;
  int row0 = blockIdx.x * 64;                   // global row = b*N + n
  #pragma unroll
  for (int r = 0; r < 12; ++r) {
    int e = t + 256*r;                // float4 index
    int ro = e >> 6;                  // 0..47
    int c4 = (e & 63) * 4;
    const float* src = (ro < 32) ? &Woff[(size_t)ro*256 + c4]
                                 : &Wattn[(size_t)(ro-32)*256 + c4];
    *(float4*)&wls[ro*256 + c4] = *(const float4*)src;
  }
  float acc[12] = {};
  for (int k0 = 0; k0 < 256; k0 += 64) {
    __syncthreads();
    #pragma unroll
    for (int r = 0; r < 2; ++r) {
      int e = t + 256*r;              // 512 chunks of 8 bf16
      int rw = e >> 3;                // 0..63
      int c8 = (e & 7) * 8;           // 0..56
      short8v v = *(const short8v*)&q[(size_t)(row0 + rw)*256 + k0 + c8];
      #pragma unroll
      for (int j = 0; j < 8; ++j) qls[(c8+j)*65 + rw] = b2f((u16)v[j]);
    }
    __syncthreads();
    #pragma unroll 4
    for (int kk = 0; kk < 64; kk += 4) {
      float q0 = qls[(kk+0)*65 + n];
      float q1 = qls[(kk+1)*65 + n];
      float q2 = qls[(kk+2)*65 + n];
      float q3 = qls[(kk+3)*65 + n];
      #pragma unroll
      for (int j = 0; j < 12; ++j) {
        float4 wv = *(const float4*)&wls[(og*12+j)*256 + k0 + kk];
        acc[j] += q0*wv.x + q1*wv.y + q2*wv.z + q3*wv.w;
      }
    }
  }
  float vals[12];
  #pragma unroll
  for (int j = 0; j < 12; ++j) {
    int o = og*12 + j;
    float bv = (o < 32) ? boff[o] : battn[o-32];
    vals[j] = acc[j] + bv;
  }
  size_t rowg = row0 + n;
  if (og < 2) {
    #pragma unroll
    for (int j = 0; j < 12; ++j) off[rowg*32 + og*12 + j] = vals[j];
  } else if (og == 2) {
    #pragma unroll
    for (int j = 0; j < 8; ++j) off[rowg*32 + 24 + j] = vals[j];
    float m = fmaxf(fmaxf(vals[8],vals[9]), fmaxf(vals[10],vals[11]));
    float e0 = expf(vals[8]-m), e1 = expf(vals[9]-m), e2 = expf(vals[10]-m), e3 = expf(vals[11]-m);
    float inv = 1.f/(e0+e1+e2+e3);
    aw[rowg*16+0]=e0*inv; aw[rowg*16+1]=e1*inv; aw[rowg*16+2]=e2*inv; aw[rowg*16+3]=e3*inv;
  } else {
    #pragma unroll
    for (int gidx = 0; gidx < 3; ++gidx) {
      float l0=vals[gidx*4+0], l1=vals[gidx*4+1], l2=vals[gidx*4+2], l3=vals[gidx*4+3];
      float m = fmaxf(fmaxf(l0,l1), fmaxf(l2,l3));
      float e0=expf(l0-m), e1=expf(l1-m), e2=expf(l2-m), e3=expf(l3-m);
      float inv = 1.f/(e0+e1+e2+e3);
      size_t base = rowg*16 + 4 + gidx*4;
      aw[base+0]=e0*inv; aw[base+1]=e1*inv; aw[base+2]=e2*inv; aw[base+3]=e3*inv;
    }
  }
}

// ---------------- K4: deformable bilinear sampling, bf16 value -> bf16 attn_out
__global__ __launch_bounds__(256) void k_sample(const u16* __restrict__ value, // (B,N,C) bf16
      const float* __restrict__ off, const float* __restrict__ aw,
      u16* __restrict__ attn_out) { // (B,N,C) bf16
  int t = threadIdx.x;
  int w = t >> 6;
  int lane = t & 63;       // = d
  int item = blockIdx.x*4 + w;          // ((b*N+n)*4 + nh)
  int nh = item & 3;
  int bn = item >> 2;
  int b  = bn >> 14;
  int n  = bn & (N_DIM-1);
  int hc = n >> 7;
  int wc = n & 127;
  size_t ob = (size_t)bn*32 + nh*8;
  size_t ab = (size_t)bn*16 + nh*4;
  size_t vbase = (size_t)(b*N_DIM)*256 + nh*64 + lane;
  float acc = 0.f;
  #pragma unroll
  for (int p = 0; p < 4; ++p) {
    float ox = off[ob + p*2 + 0];
    float oy = off[ob + p*2 + 1];
    float a  = aw[ab + p];
    float px = (float)wc + ox;
    float py = (float)hc + oy;
    float x0f = floorf(px), y0f = floorf(py);
    float wx = px - x0f, wy = py - y0f;
    int x0 = (int)x0f, y0 = (int)y0f;
    float s = 0.f;
    #pragma unroll
    for (int cy = 0; cy < 2; ++cy) {
      #pragma unroll
      for (int cx = 0; cx < 2; ++cx) {
        int xi = x0 + cx, yi = y0 + cy;
        bool valid = (xi >= 0) & (xi < W_DIM) & (yi >= 0) & (yi < H_DIM);
        int xcl = min(max(xi,0), W_DIM-1);
        int ycl = min(max(yi,0), H_DIM-1);
        float v = b2f(value[vbase + (size_t)(ycl*W_DIM + xcl)*256]);
        float wgt = (cx ? wx : 1.f-wx) * (cy ? wy : 1.f-wy);
        s += valid ? wgt*v : 0.f;
      }
    }
    acc += a * s;
  }
  attn_out[(size_t)bn*256 + nh*64 + lane] = f2b(acc);
}

// ---------------- K6: out = ao + x (residual); LN over C -> yt (B,C,N); res -> d_out (B,C,N)
__global__ __launch_bounds__(256) void k_ln2res(const float* __restrict__ ao,
                    const float* __restrict__ x,
                    const float* __restrict__ g, const float* __restrict__ bta,
                    float* __restrict__ yt, float* __restrict__ res) {
  __shared__ float tile[256*33];
  __shared__ float psum[256], psq[256];
  __shared__ float rmean[32], rstd[32];
  int t = threadIdx.x;
  int blk = blockIdx.x;
  int b = blk >> 9;
  int n0 = (blk & 511) * 32;
  // pass1: thread t = channel c; out = ao^T + x; write res (coalesced per-lane 128B)
  {
    size_t xb = ((size_t)(b*C_DIM + t))*N_DIM + n0;
    #pragma unroll
    for (int i4 = 0; i4 < 8; ++i4) {
      float4 xv = *(const float4*)&x[xb + i4*4];
      float o0 = ao[((size_t)(b*N_DIM + n0 + i4*4+0))*C_DIM + t] + xv.x;
      float o1 = ao[((size_t)(b*N_DIM + n0 + i4*4+1))*C_DIM + t] + xv.y;
      float o2 = ao[((size_t)(b*N_DIM + n0 + i4*4+2))*C_DIM + t] + xv.z;
      float o3 = ao[((size_t)(b*N_DIM + n0 + i4*4+3))*C_DIM + t] + xv.w;
      tile[t*33 + i4*4+0] = o0;
      tile[t*33 + i4*4+1] = o1;
      tile[t*33 + i4*4+2] = o2;
      tile[t*33 + i4*4+3] = o3;
      float4 rv; rv.x=o0; rv.y=o1; rv.z=o2; rv.w=o3;
      *(float4*)&res[xb + i4*4] = rv;
    }
  }
  __syncthreads();
  {
    int n = t & 31, j = t >> 5;
    float s = 0.f, s2 = 0.f;
    #pragma unroll 8
    for (int i = 0; i < 32; ++i) {
      float v = tile[(j*32+i)*33 + n];
      s += v; s2 += v*v;
    }
    psum[j*32+n] = s; psq[j*32+n] = s2;
  }
  __syncthreads();
  if (t < 32) {
    float s=0.f, s2=0.f;
    for (int j=0;j<8;++j){ s += psum[j*32+t]; s2 += psq[j*32+t]; }
    float m = s * (1.f/256.f);
    float var = s2 * (1.f/256.f) - m*m;
    rmean[t] = m; rstd[t] = rsqrtf(var + LN_EPSF);
  }
  __syncthreads();
  int nl = t & 31, cr = t >> 5;
  #pragma unroll 4
  for (int i = 0; i < 32; ++i) {
    int c = i*8 + cr;
    float v = tile[c*33 + nl];
    yt[((size_t)(b*C_DIM + c))*N_DIM + n0 + nl] = (v - rmean[nl]) * rstd[nl] * g[c] + bta[c];
  }
}

// ---------------- K7: depthwise 3x3 + SiLU gate -> h (B,128,N) f32
__global__ __launch_bounds__(256) void k_dwconv(const float* __restrict__ yt,
     const float* __restrict__ dww, const float* __restrict__ dwb,
     float* __restrict__ hb) {
  int t = threadIdx.x;
  int blk = blockIdx.x;        // b*8192 + c*64 + ht
  int ht = blk & 63; int c = (blk >> 6) & 127; int b = blk >> 13;
  int hh = t >> 7; int ww = t & 127;
  int h = ht*2 + hh;
  const float* p1 = yt + ((size_t)(b*256 + c))*N_DIM;
  const float* p2 = yt + ((size_t)(b*256 + c + 128))*N_DIM;
  float w1[9], w2[9];
  #pragma unroll
  for (int i=0;i<9;++i){ w1[i]=dww[c*9+i]; w2[i]=dww[(c+128)*9+i]; }
  float a1 = dwb[c], a2 = dwb[c+128];
  #pragma unroll
  for (int ky=0;ky<3;++ky){
    int yy = h + ky - 1;
    if (yy < 0 || yy >= H_DIM) continue;
    #pragma unroll
    for (int kx=0;kx<3;++kx){
      int xx = ww + kx - 1;
      if (xx < 0 || xx >= W_DIM) continue;
      float v1 = p1[yy*W_DIM+xx], v2 = p2[yy*W_DIM+xx];
      a1 += w1[ky*3+kx]*v1; a2 += w2[ky*3+kx]*v2;
    }
  }
  float sig = 1.f/(1.f+expf(-a1));
  hb[((size_t)(b*128+c))*N_DIM + h*W_DIM + ww] = a1*sig*a2;
}

// ---------------- K8: d_out += pr_w @ h + pr_b   (bf16 MFMA, LDS-transposed B)
// block: n-tile 64, all o=256 (wave w -> o in [w*64,w*64+64)); K=128
__global__ __launch_bounds__(256) void k_prfinal_mfma(const float* __restrict__ hsrc, // (B,128,N) f32
     const u16* __restrict__ pw,   // (256,128) bf16
     const float* __restrict__ prb,
     float* __restrict__ dout) {   // (B,256,N) f32, holds res
  __shared__ u16 hls[64*128];      // [n][k], k XOR-swizzled by ((n&7)<<3)
  int t = threadIdx.x;
  int lane = t & 63, w = t >> 6;
  int b = blockIdx.y;
  int n0 = blockIdx.x * 64;
  #pragma unroll
  for (int r = 0; r < 8; ++r) {
    int e = t + 256*r;      // 2048 float4 chunks = 128k x 16 n-chunks
    int k = e >> 4;         // 0..127
    int n4 = (e & 15) * 4;  // 0..60
    float4 v = *(const float4*)&hsrc[((size_t)(b*128 + k))*N_DIM + n0 + n4];
    float vv[4] = {v.x, v.y, v.z, v.w};
    #pragma unroll
    for (int j = 0; j < 4; ++j) {
      int n = n4 + j;
      hls[n*128 + (k ^ ((n & 7) << 3))] = f2b(vv[j]);
    }
  }
  __syncthreads();
  int l15 = lane & 15, lk = (lane >> 4) * 8;
  f32x4 acc[4][4] = {};   // [oi][nj]
  #pragma unroll
  for (int k0 = 0; k0 < 128; k0 += 32) {
    short8v af[4], bf[4];
    #pragma unroll
    for (int oi = 0; oi < 4; ++oi)
      af[oi] = *(const short8v*)&pw[(size_t)(w*64 + oi*16 + l15)*128 + k0 + lk];
    #pragma unroll
    for (int nj = 0; nj < 4; ++nj) {
      int n = nj*16 + l15;
      bf[nj] = *(const short8v*)&hls[n*128 + ((k0 + lk) ^ ((n & 7) << 3))];
    }
    #pragma unroll
    for (int oi = 0; oi < 4; ++oi)
      #pragma unroll
      for (int nj = 0; nj < 4; ++nj)
        acc[oi][nj] = __builtin_amdgcn_mfma_f32_16x16x32_bf16(af[oi], bf[nj], acc[oi][nj], 0,0,0);
  }
  int rbase = (lane >> 4) * 4;
  #pragma unroll
  for (int oi = 0; oi < 4; ++oi)
    #pragma unroll
    for (int r = 0; r < 4; ++r) {
      int o = w*64 + oi*16 + rbase + r;
      float pb = prb[o];
      #pragma unroll
      for (int nj = 0; nj < 4; ++nj) {
        int n = n0 + nj*16 + l15;
        size_t idx = ((size_t)(b*256 + o))*N_DIM + n;
        dout[idx] += acc[oi][nj][r] + pb;
      }
    }
}

extern "C" void kernel_launch(void* const* d_in, const int* in_sizes, int n_in,
                              void* d_out, int out_size, void* d_ws, size_t ws_size,
                              hipStream_t stream) {
  const float* x      = (const float*)d_in[0];
  const float* norm_g = (const float*)d_in[1];
  const float* norm_b = (const float*)d_in[2];
  const float* ffn_g  = (const float*)d_in[3];
  const float* ffn_b  = (const float*)d_in[4];
  const float* W_val  = (const float*)d_in[5];
  const float* b_val  = (const float*)d_in[6];
  const float* W_off  = (const float*)d_in[7];
  const float* b_off  = (const float*)d_in[8];
  const float* W_attn = (const float*)d_in[9];
  const float* b_attn = (const float*)d_in[10];
  const float* W_out  = (const float*)d_in[11];
  const float* b_out  = (const float*)d_in[12];
  const float* dw_w   = (const float*)d_in[13];
  const float* dw_b   = (const float*)d_in[14];
  const float* pr_w   = (const float*)d_in[15];
  const float* pr_b   = (const float*)d_in[16];
  float* outp = (float*)d_out;

  char* ws = (char*)d_ws;
  const size_t MB32 = 32u*1024u*1024u;
  // region0 (32MB): qbf (16MB) | valbf (16MB); later attnbf (16MB @0); later yt f32 (32MB)
  // region1 (32MB): ao f32 (32MB); later h f32 (16MB)
  u16*   qbf    = (u16*)(ws);
  u16*   valbf  = (u16*)(ws + 16u*1024u*1024u);
  u16*   attnbf = (u16*)(ws);                    // reuses qbf (dead after offattn)
  float* yt     = (float*)(ws);                  // reuses region0 (all dead)
  float* ao     = (float*)(ws + MB32);
  float* hbuf   = (float*)(ws + MB32);           // reuses ao (dead after ln2res)
  float* boffb  = (float*)(ws + 2u*MB32);
  float* bawb   = (float*)(ws + 2u*MB32 + 4u*1024u*1024u);
  u16*   wvbf   = (u16*)(ws + 2u*MB32 + 6u*1024u*1024u);
  u16*   wobf   = (u16*)(ws + 2u*MB32 + 6u*1024u*1024u + 131072u);
  u16*   pwbf   = (u16*)(ws + 2u*MB32 + 6u*1024u*1024u + 262144u);

  // weights -> bf16
  k_cvt<<<dim3(64),  dim3(256), 0, stream>>>(W_val, wvbf, 16384);
  k_cvt<<<dim3(64),  dim3(256), 0, stream>>>(W_out, wobf, 16384);
  k_cvt<<<dim3(32),  dim3(256), 0, stream>>>(pr_w,  pwbf, 8192);
  // 1. LN1: x -> q bf16
  k_ln1<<<dim3(1024), dim3(256), 0, stream>>>(x, norm_g, norm_b, qbf);
  // 2. value = q @ W_val^T + b_val (bf16)
  k_gemm_val_mfma<<<dim3(512), dim3(256), 0, stream>>>(qbf, wvbf, b_val, valbf);
  // 3. off / aw
  k_offattn<<<dim3(512), dim3(256), 0, stream>>>(qbf, W_off, b_off, W_attn, b_attn, boffb, bawb);
  // 4. deformable sampling -> attn_out bf16 (qbf dead)
  k_sample<<<dim3(32768), dim3(256), 0, stream>>>(valbf, boffb, bawb, attnbf);
  // 5. ao = attn_out @ W_out^T + b_out (f32, (B,N,C))
  k_gemm_out_mfma<<<dim3(512), dim3(256), 0, stream>>>(attnbf, wobf, b_out, ao);
  // 6. out = ao + x; LN -> yt (B,C,N); res -> d_out
  k_ln2res<<<dim3(1024), dim3(256), 0, stream>>>(ao, x, ffn_g, ffn_b, yt, outp);
  // 7. depthwise conv + SiLU gate: yt -> h (ao dead)
  k_dwconv<<<dim3(16384), dim3(256), 0, stream>>>(yt, dw_w, dw_b, hbuf);
  // 8. d_out += pr_w @ h + pr_b
  k_prfinal_mfma<<<dim3(256, 2), dim3(256), 0, stream>>>(hbuf, pwbf, pr_b, outp);

  (void)in_sizes; (void)n_in; (void)out_size; (void)ws_size;
}

// Round 4
// 183.875 us; speedup vs baseline: 3.9482x; 1.1765x over previous
//
#include <hip/hip_runtime.h>
#include <cmath>

typedef unsigned short u16;
typedef __attribute__((ext_vector_type(8))) short short8v;   // 8 bf16
typedef __attribute__((ext_vector_type(4))) float f32x4;

#define C_DIM 256
#define H_DIM 128
#define W_DIM 128
#define N_DIM (H_DIM*W_DIM)   // 16384
#define B_DIM 2
#define LN_EPSF 1e-5f

__device__ __forceinline__ u16 f2b(float f) {
  unsigned u = __float_as_uint(f);
  unsigned r = (u + 0x7fffu + ((u >> 16) & 1u)) >> 16;   // RNE
  return (u16)r;
}
__device__ __forceinline__ float b2f(u16 h) {
  return __uint_as_float(((unsigned)h) << 16);
}

// ---------------- K0: f32 -> bf16 conversion for W_val, W_out, pr_w (merged)
__global__ __launch_bounds__(256) void k_cvt3(const float* __restrict__ w0,
      const float* __restrict__ w1, const float* __restrict__ w2,
      u16* __restrict__ d0, u16* __restrict__ d1, u16* __restrict__ d2) {
  int i = blockIdx.x*256 + threadIdx.x;   // float4 index, 0..40959
  const float* s; u16* d; int l;
  if (i < 16384)      { s = w0; d = d0; l = i; }
  else if (i < 32768) { s = w1; d = d1; l = i - 16384; }
  else                { s = w2; d = d2; l = i - 32768; }
  float4 v = *(const float4*)&s[(size_t)l*4];
  d[l*4+0]=f2b(v.x); d[l*4+1]=f2b(v.y); d[l*4+2]=f2b(v.z); d[l*4+3]=f2b(v.w);
}

// ---------------- K1: LN over C. input x (B,C,N) -> q (B,N,C) bf16
__global__ __launch_bounds__(256) void k_ln1(const float* __restrict__ x,
                    const float* __restrict__ g, const float* __restrict__ bta,
                    u16* __restrict__ q) {
  __shared__ float tile[256*33];   // [c][n] padded
  __shared__ float psum[256], psq[256];
  __shared__ float rmean[32], rstd[32];
  int t = threadIdx.x;
  int blk = blockIdx.x;          // b*512 + ntile
  int b = blk >> 9;
  int n0 = (blk & 511) * 32;
  int nl = t & 31, cr = t >> 5;
  #pragma unroll 4
  for (int i = 0; i < 32; ++i) {
    int c = i*8 + cr;
    tile[c*33 + nl] = x[((size_t)(b*C_DIM + c))*N_DIM + n0 + nl];
  }
  __syncthreads();
  {
    int n = t & 31, j = t >> 5;
    float s = 0.f, s2 = 0.f;
    #pragma unroll 8
    for (int i = 0; i < 32; ++i) {
      float v = tile[(j*32+i)*33 + n];
      s += v; s2 += v*v;
    }
    psum[j*32+n] = s; psq[j*32+n] = s2;
  }
  __syncthreads();
  if (t < 32) {
    float s=0.f, s2=0.f;
    for (int j=0;j<8;++j){ s += psum[j*32+t]; s2 += psq[j*32+t]; }
    float m = s * (1.f/256.f);
    float var = s2 * (1.f/256.f) - m*m;
    rmean[t] = m; rstd[t] = rsqrtf(var + LN_EPSF);
  }
  __syncthreads();
  float gt = g[t], bt = bta[t];
  #pragma unroll 4
  for (int i = 0; i < 32; ++i) {
    float v = tile[t*33 + i];
    q[((size_t)(b*N_DIM + n0 + i))*C_DIM + t] = f2b((v - rmean[i]) * rstd[i] * gt + bt);
  }
}

// ---------------- K2: value = q @ W_val^T + b_val, bf16 MFMA, out bf16
__global__ __launch_bounds__(256) void k_gemm_val_mfma(const u16* __restrict__ A,
      const u16* __restrict__ Wb, const float* __restrict__ bias,
      u16* __restrict__ out) {
  int t = threadIdx.x;
  int lane = t & 63, w = t >> 6;
  int m0 = blockIdx.x * 64;
  int l15 = lane & 15, lk = (lane >> 4) * 8;
  f32x4 acc[4][4] = {};   // [mi][oj]
  float bias_v[4];
  #pragma unroll
  for (int oj = 0; oj < 4; ++oj) bias_v[oj] = bias[w*64 + oj*16 + l15];
  #pragma unroll
  for (int k0 = 0; k0 < 256; k0 += 32) {
    short8v af[4], bf[4];
    #pragma unroll
    for (int mi = 0; mi < 4; ++mi)
      af[mi] = *(const short8v*)&A[(size_t)(m0 + mi*16 + l15)*256 + k0 + lk];
    #pragma unroll
    for (int oj = 0; oj < 4; ++oj)
      bf[oj] = *(const short8v*)&Wb[(size_t)(w*64 + oj*16 + l15)*256 + k0 + lk];
    #pragma unroll
    for (int mi = 0; mi < 4; ++mi)
      #pragma unroll
      for (int oj = 0; oj < 4; ++oj)
        acc[mi][oj] = __builtin_amdgcn_mfma_f32_16x16x32_bf16(af[mi], bf[oj], acc[mi][oj], 0,0,0);
  }
  int rbase = (lane >> 4) * 4;
  #pragma unroll
  for (int mi = 0; mi < 4; ++mi)
    #pragma unroll
    for (int oj = 0; oj < 4; ++oj)
      #pragma unroll
      for (int r = 0; r < 4; ++r) {
        int m = m0 + mi*16 + rbase + r;
        int o = w*64 + oj*16 + l15;
        out[(size_t)m*256 + o] = f2b(acc[mi][oj][r] + bias_v[oj]);
      }
}

// ---------------- K5: ao = attn_out @ W_out^T + b_out, bf16 MFMA, out f32 (B,N,C)
__global__ __launch_bounds__(256) void k_gemm_out_mfma(const u16* __restrict__ A,
      const u16* __restrict__ Wb, const float* __restrict__ bias,
      float* __restrict__ out) {
  int t = threadIdx.x;
  int lane = t & 63, w = t >> 6;
  int m0 = blockIdx.x * 64;
  int l15 = lane & 15, lk = (lane >> 4) * 8;
  f32x4 acc[4][4] = {};
  float bias_v[4];
  #pragma unroll
  for (int oj = 0; oj < 4; ++oj) bias_v[oj] = bias[w*64 + oj*16 + l15];
  #pragma unroll
  for (int k0 = 0; k0 < 256; k0 += 32) {
    short8v af[4], bf[4];
    #pragma unroll
    for (int mi = 0; mi < 4; ++mi)
      af[mi] = *(const short8v*)&A[(size_t)(m0 + mi*16 + l15)*256 + k0 + lk];
    #pragma unroll
    for (int oj = 0; oj < 4; ++oj)
      bf[oj] = *(const short8v*)&Wb[(size_t)(w*64 + oj*16 + l15)*256 + k0 + lk];
    #pragma unroll
    for (int mi = 0; mi < 4; ++mi)
      #pragma unroll
      for (int oj = 0; oj < 4; ++oj)
        acc[mi][oj] = __builtin_amdgcn_mfma_f32_16x16x32_bf16(af[mi], bf[oj], acc[mi][oj], 0,0,0);
  }
  int rbase = (lane >> 4) * 4;
  #pragma unroll
  for (int mi = 0; mi < 4; ++mi)
    #pragma unroll
    for (int oj = 0; oj < 4; ++oj)
      #pragma unroll
      for (int r = 0; r < 4; ++r) {
        int m = m0 + mi*16 + rbase + r;
        int o = w*64 + oj*16 + l15;
        out[(size_t)m*256 + o] = acc[mi][oj][r] + bias_v[oj];
      }
}

// ---------------- K3: off/attn GEMM (48 outputs) + softmax, q in bf16
__global__ __launch_bounds__(256) void k_offattn(const u16* __restrict__ q,
      const float* __restrict__ Woff, const float* __restrict__ boff,
      const float* __restrict__ Wattn, const float* __restrict__ battn,
      float* __restrict__ off, float* __restrict__ aw) {
  __shared__ __align__(16) float wls[48*256];   // [o][k]
  __shared__ float qls[64*65];                  // [k][n] padded
  int t = threadIdx.x;
  int n = t & 63, og = t >> 6;
  int row0 = blockIdx.x * 64;                   // global row = b*N + n
  #pragma unroll
  for (int r = 0; r < 12; ++r) {
    int e = t + 256*r;                // float4 index
    int ro = e >> 6;                  // 0..47
    int c4 = (e & 63) * 4;
    const float* src = (ro < 32) ? &Woff[(size_t)ro*256 + c4]
                                 : &Wattn[(size_t)(ro-32)*256 + c4];
    *(float4*)&wls[ro*256 + c4] = *(const float4*)src;
  }
  float acc[12] = {};
  for (int k0 = 0; k0 < 256; k0 += 64) {
    __syncthreads();
    #pragma unroll
    for (int r = 0; r < 2; ++r) {
      int e = t + 256*r;              // 512 chunks of 8 bf16
      int rw = e >> 3;                // 0..63
      int c8 = (e & 7) * 8;           // 0..56
      short8v v = *(const short8v*)&q[(size_t)(row0 + rw)*256 + k0 + c8];
      #pragma unroll
      for (int j = 0; j < 8; ++j) qls[(c8+j)*65 + rw] = b2f((u16)v[j]);
    }
    __syncthreads();
    #pragma unroll 4
    for (int kk = 0; kk < 64; kk += 4) {
      float q0 = qls[(kk+0)*65 + n];
      float q1 = qls[(kk+1)*65 + n];
      float q2 = qls[(kk+2)*65 + n];
      float q3 = qls[(kk+3)*65 + n];
      #pragma unroll
      for (int j = 0; j < 12; ++j) {
        float4 wv = *(const float4*)&wls[(og*12+j)*256 + k0 + kk];
        acc[j] += q0*wv.x + q1*wv.y + q2*wv.z + q3*wv.w;
      }
    }
  }
  float vals[12];
  #pragma unroll
  for (int j = 0; j < 12; ++j) {
    int o = og*12 + j;
    float bv = (o < 32) ? boff[o] : battn[o-32];
    vals[j] = acc[j] + bv;
  }
  size_t rowg = row0 + n;
  if (og < 2) {
    #pragma unroll
    for (int j = 0; j < 12; ++j) off[rowg*32 + og*12 + j] = vals[j];
  } else if (og == 2) {
    #pragma unroll
    for (int j = 0; j < 8; ++j) off[rowg*32 + 24 + j] = vals[j];
    float m = fmaxf(fmaxf(vals[8],vals[9]), fmaxf(vals[10],vals[11]));
    float e0 = expf(vals[8]-m), e1 = expf(vals[9]-m), e2 = expf(vals[10]-m), e3 = expf(vals[11]-m);
    float inv = 1.f/(e0+e1+e2+e3);
    aw[rowg*16+0]=e0*inv; aw[rowg*16+1]=e1*inv; aw[rowg*16+2]=e2*inv; aw[rowg*16+3]=e3*inv;
  } else {
    #pragma unroll
    for (int gidx = 0; gidx < 3; ++gidx) {
      float l0=vals[gidx*4+0], l1=vals[gidx*4+1], l2=vals[gidx*4+2], l3=vals[gidx*4+3];
      float m = fmaxf(fmaxf(l0,l1), fmaxf(l2,l3));
      float e0=expf(l0-m), e1=expf(l1-m), e2=expf(l2-m), e3=expf(l3-m);
      float inv = 1.f/(e0+e1+e2+e3);
      size_t base = rowg*16 + 4 + gidx*4;
      aw[base+0]=e0*inv; aw[base+1]=e1*inv; aw[base+2]=e2*inv; aw[base+3]=e3*inv;
    }
  }
}

// ---------------- K4: deformable bilinear sampling (rewritten)
// wave per (b,n); lane = nh*16 + dgroup; each lane does 4 channels via ushort4
__global__ __launch_bounds__(256) void k_sample(const u16* __restrict__ value, // (B,N,C) bf16
      const float* __restrict__ off, const float* __restrict__ aw,
      u16* __restrict__ attn_out) { // (B,N,C) bf16
  int t = threadIdx.x;
  int wv = t >> 6, lane = t & 63;
  int bn = blockIdx.x*4 + wv;            // b*N + n
  int b = bn >> 14, n = bn & (N_DIM-1);
  int hc = n >> 7, wc = n & 127;
  int nh = lane >> 4;
  int dg = (lane & 15) * 4;
  int vbase = b*(N_DIM*256) + nh*64 + dg;     // fits int32
  const float* op = &off[(size_t)bn*32 + nh*8];
  const float* ap = &aw[(size_t)bn*16 + nh*4];
  float acc0=0.f, acc1=0.f, acc2=0.f, acc3=0.f;
  #pragma unroll
  for (int p = 0; p < 4; ++p) {
    float ox = op[p*2+0], oy = op[p*2+1];
    float a  = ap[p];
    float px = (float)wc + ox;
    float py = (float)hc + oy;
    float x0f = floorf(px), y0f = floorf(py);
    float wx = px - x0f, wy = py - y0f;
    int x0 = (int)x0f, y0 = (int)y0f;
    int x1 = x0 + 1, y1 = y0 + 1;
    float fx0 = (1.f - wx) * ((x0 >= 0 && x0 < W_DIM) ? 1.f : 0.f);
    float fx1 = wx         * ((x1 >= 0 && x1 < W_DIM) ? 1.f : 0.f);
    float fy0 = a * (1.f - wy) * ((y0 >= 0 && y0 < H_DIM) ? 1.f : 0.f);
    float fy1 = a * wy         * ((y1 >= 0 && y1 < H_DIM) ? 1.f : 0.f);
    int xc0 = min(max(x0,0),W_DIM-1), xc1 = min(max(x1,0),W_DIM-1);
    int yc0 = min(max(y0,0),H_DIM-1), yc1 = min(max(y1,0),H_DIM-1);
    int r0 = yc0*W_DIM, r1 = yc1*W_DIM;
    {
      ushort4 v = *(const ushort4*)&value[vbase + (r0+xc0)*256];
      float wgt = fx0*fy0;
      acc0 += wgt*b2f(v.x); acc1 += wgt*b2f(v.y); acc2 += wgt*b2f(v.z); acc3 += wgt*b2f(v.w);
    }
    {
      ushort4 v = *(const ushort4*)&value[vbase + (r0+xc1)*256];
      float wgt = fx1*fy0;
      acc0 += wgt*b2f(v.x); acc1 += wgt*b2f(v.y); acc2 += wgt*b2f(v.z); acc3 += wgt*b2f(v.w);
    }
    {
      ushort4 v = *(const ushort4*)&value[vbase + (r1+xc0)*256];
      float wgt = fx0*fy1;
      acc0 += wgt*b2f(v.x); acc1 += wgt*b2f(v.y); acc2 += wgt*b2f(v.z); acc3 += wgt*b2f(v.w);
    }
    {
      ushort4 v = *(const ushort4*)&value[vbase + (r1+xc1)*256];
      float wgt = fx1*fy1;
      acc0 += wgt*b2f(v.x); acc1 += wgt*b2f(v.y); acc2 += wgt*b2f(v.z); acc3 += wgt*b2f(v.w);
    }
  }
  ushort4 o;
  o.x = f2b(acc0); o.y = f2b(acc1); o.z = f2b(acc2); o.w = f2b(acc3);
  *(ushort4*)&attn_out[(size_t)bn*256 + nh*64 + dg] = o;
}

// ---------------- K6: out = ao + x; LN over C -> yt (B,C,N) bf16; res -> d_out f32
__global__ __launch_bounds__(256) void k_ln2res(const float* __restrict__ ao,
                    const float* __restrict__ x,
                    const float* __restrict__ g, const float* __restrict__ bta,
                    u16* __restrict__ yt, float* __restrict__ res) {
  __shared__ float tile[256*33];
  __shared__ float psum[256], psq[256];
  __shared__ float rmean[32], rstd[32];
  int t = threadIdx.x;
  int blk = blockIdx.x;
  int b = blk >> 9;
  int n0 = (blk & 511) * 32;
  {
    size_t xb = ((size_t)(b*C_DIM + t))*N_DIM + n0;
    #pragma unroll
    for (int i4 = 0; i4 < 8; ++i4) {
      float4 xv = *(const float4*)&x[xb + i4*4];
      float o0 = ao[((size_t)(b*N_DIM + n0 + i4*4+0))*C_DIM + t] + xv.x;
      float o1 = ao[((size_t)(b*N_DIM + n0 + i4*4+1))*C_DIM + t] + xv.y;
      float o2 = ao[((size_t)(b*N_DIM + n0 + i4*4+2))*C_DIM + t] + xv.z;
      float o3 = ao[((size_t)(b*N_DIM + n0 + i4*4+3))*C_DIM + t] + xv.w;
      tile[t*33 + i4*4+0] = o0;
      tile[t*33 + i4*4+1] = o1;
      tile[t*33 + i4*4+2] = o2;
      tile[t*33 + i4*4+3] = o3;
      float4 rv; rv.x=o0; rv.y=o1; rv.z=o2; rv.w=o3;
      *(float4*)&res[xb + i4*4] = rv;
    }
  }
  __syncthreads();
  {
    int n = t & 31, j = t >> 5;
    float s = 0.f, s2 = 0.f;
    #pragma unroll 8
    for (int i = 0; i < 32; ++i) {
      float v = tile[(j*32+i)*33 + n];
      s += v; s2 += v*v;
    }
    psum[j*32+n] = s; psq[j*32+n] = s2;
  }
  __syncthreads();
  if (t < 32) {
    float s=0.f, s2=0.f;
    for (int j=0;j<8;++j){ s += psum[j*32+t]; s2 += psq[j*32+t]; }
    float m = s * (1.f/256.f);
    float var = s2 * (1.f/256.f) - m*m;
    rmean[t] = m; rstd[t] = rsqrtf(var + LN_EPSF);
  }
  __syncthreads();
  int nl = t & 31, cr = t >> 5;
  #pragma unroll 4
  for (int i = 0; i < 32; ++i) {
    int c = i*8 + cr;
    float v = tile[c*33 + nl];
    yt[((size_t)(b*C_DIM + c))*N_DIM + n0 + nl] = f2b((v - rmean[nl]) * rstd[nl] * g[c] + bta[c]);
  }
}

// ---------------- K7: depthwise 3x3 + SiLU gate, bf16 in -> bf16 h (B,128,N)
__global__ __launch_bounds__(256) void k_dwconv(const u16* __restrict__ yt,
     const float* __restrict__ dww, const float* __restrict__ dwb,
     u16* __restrict__ hb) {
  int t = threadIdx.x;
  int blk = blockIdx.x;        // b*8192 + c*64 + ht
  int ht = blk & 63; int c = (blk >> 6) & 127; int b = blk >> 13;
  int hh = t >> 7; int ww = t & 127;
  int h = ht*2 + hh;
  const u16* p1 = yt + ((size_t)(b*256 + c))*N_DIM;
  const u16* p2 = yt + ((size_t)(b*256 + c + 128))*N_DIM;
  float w1[9], w2[9];
  #pragma unroll
  for (int i=0;i<9;++i){ w1[i]=dww[c*9+i]; w2[i]=dww[(c+128)*9+i]; }
  float a1 = dwb[c], a2 = dwb[c+128];
  #pragma unroll
  for (int ky=0;ky<3;++ky){
    int yy = h + ky - 1;
    if (yy < 0 || yy >= H_DIM) continue;
    #pragma unroll
    for (int kx=0;kx<3;++kx){
      int xx = ww + kx - 1;
      if (xx < 0 || xx >= W_DIM) continue;
      float v1 = b2f(p1[yy*W_DIM+xx]), v2 = b2f(p2[yy*W_DIM+xx]);
      a1 += w1[ky*3+kx]*v1; a2 += w2[ky*3+kx]*v2;
    }
  }
  float sig = 1.f/(1.f+expf(-a1));
  hb[((size_t)(b*128+c))*N_DIM + h*W_DIM + ww] = f2b(a1*sig*a2);
}

// ---------------- K8: d_out += pr_w @ h + pr_b   (bf16 MFMA, LDS-transposed B)
__global__ __launch_bounds__(256) void k_prfinal_mfma(const u16* __restrict__ hsrc, // (B,128,N) bf16
     const u16* __restrict__ pw,   // (256,128) bf16
     const float* __restrict__ prb,
     float* __restrict__ dout) {   // (B,256,N) f32, holds res
  __shared__ u16 hls[64*128];      // [n][k], k XOR-swizzled by ((n&7)<<3)
  int t = threadIdx.x;
  int lane = t & 63, w = t >> 6;
  int b = blockIdx.y;
  int n0 = blockIdx.x * 64;
  #pragma unroll
  for (int r = 0; r < 4; ++r) {
    int e = t + 256*r;      // 1024 ushort8 chunks: 128 k x 8 n-chunks
    int k = e >> 3;         // 0..127
    int n8 = (e & 7) * 8;   // 0..56
    short8v v = *(const short8v*)&hsrc[((size_t)(b*128 + k))*N_DIM + n0 + n8];
    #pragma unroll
    for (int j = 0; j < 8; ++j) {
      int n = n8 + j;
      hls[n*128 + (k ^ ((n & 7) << 3))] = (u16)v[j];
    }
  }
  __syncthreads();
  int l15 = lane & 15, lk = (lane >> 4) * 8;
  f32x4 acc[4][4] = {};   // [oi][nj]
  #pragma unroll
  for (int k0 = 0; k0 < 128; k0 += 32) {
    short8v af[4], bf[4];
    #pragma unroll
    for (int oi = 0; oi < 4; ++oi)
      af[oi] = *(const short8v*)&pw[(size_t)(w*64 + oi*16 + l15)*128 + k0 + lk];
    #pragma unroll
    for (int nj = 0; nj < 4; ++nj) {
      int n = nj*16 + l15;
      bf[nj] = *(const short8v*)&hls[n*128 + ((k0 + lk) ^ ((n & 7) << 3))];
    }
    #pragma unroll
    for (int oi = 0; oi < 4; ++oi)
      #pragma unroll
      for (int nj = 0; nj < 4; ++nj)
        acc[oi][nj] = __builtin_amdgcn_mfma_f32_16x16x32_bf16(af[oi], bf[nj], acc[oi][nj], 0,0,0);
  }
  int rbase = (lane >> 4) * 4;
  #pragma unroll
  for (int oi = 0; oi < 4; ++oi)
    #pragma unroll
    for (int r = 0; r < 4; ++r) {
      int o = w*64 + oi*16 + rbase + r;
      float pb = prb[o];
      #pragma unroll
      for (int nj = 0; nj < 4; ++nj) {
        int n = n0 + nj*16 + l15;
        size_t idx = ((size_t)(b*256 + o))*N_DIM + n;
        dout[idx] += acc[oi][nj][r] + pb;
      }
    }
}

extern "C" void kernel_launch(void* const* d_in, const int* in_sizes, int n_in,
                              void* d_out, int out_size, void* d_ws, size_t ws_size,
                              hipStream_t stream) {
  const float* x      = (const float*)d_in[0];
  const float* norm_g = (const float*)d_in[1];
  const float* norm_b = (const float*)d_in[2];
  const float* ffn_g  = (const float*)d_in[3];
  const float* ffn_b  = (const float*)d_in[4];
  const float* W_val  = (const float*)d_in[5];
  const float* b_val  = (const float*)d_in[6];
  const float* W_off  = (const float*)d_in[7];
  const float* b_off  = (const float*)d_in[8];
  const float* W_attn = (const float*)d_in[9];
  const float* b_attn = (const float*)d_in[10];
  const float* W_out  = (const float*)d_in[11];
  const float* b_out  = (const float*)d_in[12];
  const float* dw_w   = (const float*)d_in[13];
  const float* dw_b   = (const float*)d_in[14];
  const float* pr_w   = (const float*)d_in[15];
  const float* pr_b   = (const float*)d_in[16];
  float* outp = (float*)d_out;

  char* ws = (char*)d_ws;
  const size_t MB32 = 32u*1024u*1024u;
  // region0 (32MB): qbf (16MB) | valbf (16MB); later attnbf (@0); later yt bf16 (16MB)
  // region1 (32MB): ao f32 (32MB); later h bf16 (8.4MB)
  u16*   qbf    = (u16*)(ws);
  u16*   valbf  = (u16*)(ws + 16u*1024u*1024u);
  u16*   attnbf = (u16*)(ws);                    // reuses qbf (dead after offattn)
  u16*   yt     = (u16*)(ws);                    // reuses region0
  float* ao     = (float*)(ws + MB32);
  u16*   hbuf   = (u16*)(ws + MB32);             // reuses ao (dead after ln2res)
  float* boffb  = (float*)(ws + 2u*MB32);
  float* bawb   = (float*)(ws + 2u*MB32 + 4u*1024u*1024u);
  u16*   wvbf   = (u16*)(ws + 2u*MB32 + 6u*1024u*1024u);
  u16*   wobf   = (u16*)(ws + 2u*MB32 + 6u*1024u*1024u + 131072u);
  u16*   pwbf   = (u16*)(ws + 2u*MB32 + 6u*1024u*1024u + 262144u);

  // weights -> bf16 (one launch)
  k_cvt3<<<dim3(160), dim3(256), 0, stream>>>(W_val, W_out, pr_w, wvbf, wobf, pwbf);
  // 1. LN1: x -> q bf16
  k_ln1<<<dim3(1024), dim3(256), 0, stream>>>(x, norm_g, norm_b, qbf);
  // 2. value = q @ W_val^T + b_val (bf16)
  k_gemm_val_mfma<<<dim3(512), dim3(256), 0, stream>>>(qbf, wvbf, b_val, valbf);
  // 3. off / aw
  k_offattn<<<dim3(512), dim3(256), 0, stream>>>(qbf, W_off, b_off, W_attn, b_attn, boffb, bawb);
  // 4. deformable sampling -> attn_out bf16 (qbf dead)
  k_sample<<<dim3(8192), dim3(256), 0, stream>>>(valbf, boffb, bawb, attnbf);
  // 5. ao = attn_out @ W_out^T + b_out (f32, (B,N,C))
  k_gemm_out_mfma<<<dim3(512), dim3(256), 0, stream>>>(attnbf, wobf, b_out, ao);
  // 6. out = ao + x; LN -> yt bf16 (B,C,N); res -> d_out
  k_ln2res<<<dim3(1024), dim3(256), 0, stream>>>(ao, x, ffn_g, ffn_b, yt, outp);
  // 7. depthwise conv + SiLU gate: yt -> h bf16 (ao dead)
  k_dwconv<<<dim3(16384), dim3(256), 0, stream>>>(yt, dw_w, dw_b, hbuf);
  // 8. d_out += pr_w @ h + pr_b
  k_prfinal_mfma<<<dim3(256, 2), dim3(256), 0, stream>>>(hbuf, pwbf, pr_b, outp);

  (void)in_sizes; (void)n_in; (void)out_size; (void)ws_size;
}

// Round 5
// 153.020 us; speedup vs baseline: 4.7443x; 1.2016x over previous
//
#include <hip/hip_runtime.h>
#include <cmath>

typedef unsigned short u16;
typedef __attribute__((ext_vector_type(8))) short short8v;   // 8 bf16
typedef __attribute__((ext_vector_type(4))) float f32x4;

#define C_DIM 256
#define H_DIM 128
#define W_DIM 128
#define N_DIM (H_DIM*W_DIM)   // 16384
#define B_DIM 2
#define LN_EPSF 1e-5f

__device__ __forceinline__ u16 f2b(float f) {
  unsigned u = __float_as_uint(f);
  unsigned r = (u + 0x7fffu + ((u >> 16) & 1u)) >> 16;   // RNE
  return (u16)r;
}
__device__ __forceinline__ float b2f(u16 h) {
  return __uint_as_float(((unsigned)h) << 16);
}

// ---------------- K0: f32 -> bf16 conversion: W_val, W_out, pr_w, W_off|W_attn (combined)
__global__ __launch_bounds__(256) void k_cvt5(const float* __restrict__ w0,
      const float* __restrict__ w1, const float* __restrict__ w2,
      const float* __restrict__ w3, const float* __restrict__ w4,
      u16* __restrict__ d0, u16* __restrict__ d1, u16* __restrict__ d2,
      u16* __restrict__ d3) {
  int i = blockIdx.x*256 + threadIdx.x;   // float4 index
  const float* s; u16* d; int l;
  if (i < 16384)      { s = w0; d = d0;        l = i; }
  else if (i < 32768) { s = w1; d = d1;        l = i - 16384; }
  else if (i < 40960) { s = w2; d = d2;        l = i - 32768; }
  else if (i < 43008) { s = w3; d = d3;        l = i - 40960; }
  else if (i < 44032) { s = w4; d = d3 + 8192; l = i - 43008; }
  else return;
  float4 v = *(const float4*)&s[(size_t)l*4];
  d[l*4+0]=f2b(v.x); d[l*4+1]=f2b(v.y); d[l*4+2]=f2b(v.z); d[l*4+3]=f2b(v.w);
}

// ---------------- K1: LN over C. input x (B,C,N) -> q (B,N,C) bf16
__global__ __launch_bounds__(256) void k_ln1(const float* __restrict__ x,
                    const float* __restrict__ g, const float* __restrict__ bta,
                    u16* __restrict__ q) {
  __shared__ float tile[256*33];   // [c][n] padded
  __shared__ float psum[256], psq[256];
  __shared__ float rmean[32], rstd[32];
  int t = threadIdx.x;
  int blk = blockIdx.x;          // b*512 + ntile
  int b = blk >> 9;
  int n0 = (blk & 511) * 32;
  int nl = t & 31, cr = t >> 5;
  #pragma unroll 4
  for (int i = 0; i < 32; ++i) {
    int c = i*8 + cr;
    tile[c*33 + nl] = x[((size_t)(b*C_DIM + c))*N_DIM + n0 + nl];
  }
  __syncthreads();
  {
    int n = t & 31, j = t >> 5;
    float s = 0.f, s2 = 0.f;
    #pragma unroll 8
    for (int i = 0; i < 32; ++i) {
      float v = tile[(j*32+i)*33 + n];
      s += v; s2 += v*v;
    }
    psum[j*32+n] = s; psq[j*32+n] = s2;
  }
  __syncthreads();
  if (t < 32) {
    float s=0.f, s2=0.f;
    for (int j=0;j<8;++j){ s += psum[j*32+t]; s2 += psq[j*32+t]; }
    float m = s * (1.f/256.f);
    float var = s2 * (1.f/256.f) - m*m;
    rmean[t] = m; rstd[t] = rsqrtf(var + LN_EPSF);
  }
  __syncthreads();
  float gt = g[t], bt = bta[t];
  #pragma unroll 4
  for (int i = 0; i < 32; ++i) {
    float v = tile[t*33 + i];
    q[((size_t)(b*N_DIM + n0 + i))*C_DIM + t] = f2b((v - rmean[i]) * rstd[i] * gt + bt);
  }
}

// ---------------- K2: value = q @ W_val^T + b_val, bf16 MFMA, out bf16
__global__ __launch_bounds__(256) void k_gemm_val_mfma(const u16* __restrict__ A,
      const u16* __restrict__ Wb, const float* __restrict__ bias,
      u16* __restrict__ out) {
  int t = threadIdx.x;
  int lane = t & 63, w = t >> 6;
  int m0 = blockIdx.x * 64;
  int l15 = lane & 15, lk = (lane >> 4) * 8;
  f32x4 acc[4][4] = {};   // [mi][oj]
  float bias_v[4];
  #pragma unroll
  for (int oj = 0; oj < 4; ++oj) bias_v[oj] = bias[w*64 + oj*16 + l15];
  #pragma unroll
  for (int k0 = 0; k0 < 256; k0 += 32) {
    short8v af[4], bf[4];
    #pragma unroll
    for (int mi = 0; mi < 4; ++mi)
      af[mi] = *(const short8v*)&A[(size_t)(m0 + mi*16 + l15)*256 + k0 + lk];
    #pragma unroll
    for (int oj = 0; oj < 4; ++oj)
      bf[oj] = *(const short8v*)&Wb[(size_t)(w*64 + oj*16 + l15)*256 + k0 + lk];
    #pragma unroll
    for (int mi = 0; mi < 4; ++mi)
      #pragma unroll
      for (int oj = 0; oj < 4; ++oj)
        acc[mi][oj] = __builtin_amdgcn_mfma_f32_16x16x32_bf16(af[mi], bf[oj], acc[mi][oj], 0,0,0);
  }
  int rbase = (lane >> 4) * 4;
  #pragma unroll
  for (int mi = 0; mi < 4; ++mi)
    #pragma unroll
    for (int oj = 0; oj < 4; ++oj)
      #pragma unroll
      for (int r = 0; r < 4; ++r) {
        int m = m0 + mi*16 + rbase + r;
        int o = w*64 + oj*16 + l15;
        out[(size_t)m*256 + o] = f2b(acc[mi][oj][r] + bias_v[oj]);
      }
}

// ---------------- K5: ao = attn_out @ W_out^T + b_out, bf16 MFMA, out bf16 (B,N,C)
__global__ __launch_bounds__(256) void k_gemm_out_mfma(const u16* __restrict__ A,
      const u16* __restrict__ Wb, const float* __restrict__ bias,
      u16* __restrict__ out) {
  int t = threadIdx.x;
  int lane = t & 63, w = t >> 6;
  int m0 = blockIdx.x * 64;
  int l15 = lane & 15, lk = (lane >> 4) * 8;
  f32x4 acc[4][4] = {};
  float bias_v[4];
  #pragma unroll
  for (int oj = 0; oj < 4; ++oj) bias_v[oj] = bias[w*64 + oj*16 + l15];
  #pragma unroll
  for (int k0 = 0; k0 < 256; k0 += 32) {
    short8v af[4], bf[4];
    #pragma unroll
    for (int mi = 0; mi < 4; ++mi)
      af[mi] = *(const short8v*)&A[(size_t)(m0 + mi*16 + l15)*256 + k0 + lk];
    #pragma unroll
    for (int oj = 0; oj < 4; ++oj)
      bf[oj] = *(const short8v*)&Wb[(size_t)(w*64 + oj*16 + l15)*256 + k0 + lk];
    #pragma unroll
    for (int mi = 0; mi < 4; ++mi)
      #pragma unroll
      for (int oj = 0; oj < 4; ++oj)
        acc[mi][oj] = __builtin_amdgcn_mfma_f32_16x16x32_bf16(af[mi], bf[oj], acc[mi][oj], 0,0,0);
  }
  int rbase = (lane >> 4) * 4;
  #pragma unroll
  for (int mi = 0; mi < 4; ++mi)
    #pragma unroll
    for (int oj = 0; oj < 4; ++oj)
      #pragma unroll
      for (int r = 0; r < 4; ++r) {
        int m = m0 + mi*16 + rbase + r;
        int o = w*64 + oj*16 + l15;
        out[(size_t)m*256 + o] = f2b(acc[mi][oj][r] + bias_v[oj]);
      }
}

// ---------------- K3: off/attn via MFMA + in-register softmax
// wab (48x256 bf16): rows 0..31 = W_off, 32..47 = W_attn. Block = 64 rows, wave w -> 16 rows.
__global__ __launch_bounds__(256) void k_offattn_mfma(const u16* __restrict__ q,
      const u16* __restrict__ wab, const float* __restrict__ boff,
      const float* __restrict__ battn,
      float* __restrict__ off, float* __restrict__ aw) {
  int t = threadIdx.x;
  int lane = t & 63, w = t >> 6;
  int m0 = blockIdx.x * 64 + w*16;
  int l15 = lane & 15, lk = (lane >> 4) * 8;
  f32x4 acc[3] = {};
  #pragma unroll
  for (int k0 = 0; k0 < 256; k0 += 32) {
    short8v af = *(const short8v*)&q[(size_t)(m0 + l15)*256 + k0 + lk];
    #pragma unroll
    for (int oj = 0; oj < 3; ++oj) {
      short8v bf = *(const short8v*)&wab[(size_t)(oj*16 + l15)*256 + k0 + lk];
      acc[oj] = __builtin_amdgcn_mfma_f32_16x16x32_bf16(af, bf, acc[oj], 0,0,0);
    }
  }
  int rbase = (lane >> 4) * 4;
  // off outputs (o = 0..31)
  #pragma unroll
  for (int oj = 0; oj < 2; ++oj) {
    int o = oj*16 + l15;
    float bv = boff[o];
    #pragma unroll
    for (int r = 0; r < 4; ++r) {
      int row = m0 + rbase + r;
      off[(size_t)row*32 + o] = acc[oj][r] + bv;
    }
  }
  // attn logits (col l15 = nh*4+p) -> softmax over the 4-lane group
  {
    float bv = battn[l15];
    #pragma unroll
    for (int r = 0; r < 4; ++r) {
      float v = acc[2][r] + bv;
      float mx = fmaxf(v, __shfl_xor(v, 1));
      mx = fmaxf(mx, __shfl_xor(mx, 2));
      float e = expf(v - mx);
      float s = e + __shfl_xor(e, 1);
      s = s + __shfl_xor(s, 2);
      int row = m0 + rbase + r;
      aw[(size_t)row*16 + l15] = e / s;
    }
  }
}

// ---------------- K4: deformable bilinear sampling
// wave per (b,n); lane = nh*16 + dgroup; each lane does 4 channels via ushort4
__global__ __launch_bounds__(256) void k_sample(const u16* __restrict__ value, // (B,N,C) bf16
      const float* __restrict__ off, const float* __restrict__ aw,
      u16* __restrict__ attn_out) { // (B,N,C) bf16
  int t = threadIdx.x;
  int wv = t >> 6, lane = t & 63;
  int bn = blockIdx.x*4 + wv;            // b*N + n
  int b = bn >> 14, n = bn & (N_DIM-1);
  int hc = n >> 7, wc = n & 127;
  int nh = lane >> 4;
  int dg = (lane & 15) * 4;
  int vbase = b*(N_DIM*256) + nh*64 + dg;     // fits int32
  const float* op = &off[(size_t)bn*32 + nh*8];
  const float* ap = &aw[(size_t)bn*16 + nh*4];
  float acc0=0.f, acc1=0.f, acc2=0.f, acc3=0.f;
  #pragma unroll
  for (int p = 0; p < 4; ++p) {
    float ox = op[p*2+0], oy = op[p*2+1];
    float a  = ap[p];
    float px = (float)wc + ox;
    float py = (float)hc + oy;
    float x0f = floorf(px), y0f = floorf(py);
    float wx = px - x0f, wy = py - y0f;
    int x0 = (int)x0f, y0 = (int)y0f;
    int x1 = x0 + 1, y1 = y0 + 1;
    float fx0 = (1.f - wx) * ((x0 >= 0 && x0 < W_DIM) ? 1.f : 0.f);
    float fx1 = wx         * ((x1 >= 0 && x1 < W_DIM) ? 1.f : 0.f);
    float fy0 = a * (1.f - wy) * ((y0 >= 0 && y0 < H_DIM) ? 1.f : 0.f);
    float fy1 = a * wy         * ((y1 >= 0 && y1 < H_DIM) ? 1.f : 0.f);
    int xc0 = min(max(x0,0),W_DIM-1), xc1 = min(max(x1,0),W_DIM-1);
    int yc0 = min(max(y0,0),H_DIM-1), yc1 = min(max(y1,0),H_DIM-1);
    int r0 = yc0*W_DIM, r1 = yc1*W_DIM;
    {
      ushort4 v = *(const ushort4*)&value[vbase + (r0+xc0)*256];
      float wgt = fx0*fy0;
      acc0 += wgt*b2f(v.x); acc1 += wgt*b2f(v.y); acc2 += wgt*b2f(v.z); acc3 += wgt*b2f(v.w);
    }
    {
      ushort4 v = *(const ushort4*)&value[vbase + (r0+xc1)*256];
      float wgt = fx1*fy0;
      acc0 += wgt*b2f(v.x); acc1 += wgt*b2f(v.y); acc2 += wgt*b2f(v.z); acc3 += wgt*b2f(v.w);
    }
    {
      ushort4 v = *(const ushort4*)&value[vbase + (r1+xc0)*256];
      float wgt = fx0*fy1;
      acc0 += wgt*b2f(v.x); acc1 += wgt*b2f(v.y); acc2 += wgt*b2f(v.z); acc3 += wgt*b2f(v.w);
    }
    {
      ushort4 v = *(const ushort4*)&value[vbase + (r1+xc1)*256];
      float wgt = fx1*fy1;
      acc0 += wgt*b2f(v.x); acc1 += wgt*b2f(v.y); acc2 += wgt*b2f(v.z); acc3 += wgt*b2f(v.w);
    }
  }
  ushort4 o;
  o.x = f2b(acc0); o.y = f2b(acc1); o.z = f2b(acc2); o.w = f2b(acc3);
  *(ushort4*)&attn_out[(size_t)bn*256 + nh*64 + dg] = o;
}

// ---------------- K6: out = ao + x; LN over C -> yt (B,C,N) bf16; res -> bf16 (B,C,N)
__global__ __launch_bounds__(256) void k_ln2res(const u16* __restrict__ ao,
                    const float* __restrict__ x,
                    const float* __restrict__ g, const float* __restrict__ bta,
                    u16* __restrict__ yt, u16* __restrict__ res) {
  __shared__ float tile[256*33];
  __shared__ float psum[256], psq[256];
  __shared__ float rmean[32], rstd[32];
  int t = threadIdx.x;
  int blk = blockIdx.x;
  int b = blk >> 9;
  int n0 = (blk & 511) * 32;
  {
    size_t xb = ((size_t)(b*C_DIM + t))*N_DIM + n0;
    #pragma unroll
    for (int i4 = 0; i4 < 8; ++i4) {
      float4 xv = *(const float4*)&x[xb + i4*4];
      float o0 = b2f(ao[((size_t)(b*N_DIM + n0 + i4*4+0))*C_DIM + t]) + xv.x;
      float o1 = b2f(ao[((size_t)(b*N_DIM + n0 + i4*4+1))*C_DIM + t]) + xv.y;
      float o2 = b2f(ao[((size_t)(b*N_DIM + n0 + i4*4+2))*C_DIM + t]) + xv.z;
      float o3 = b2f(ao[((size_t)(b*N_DIM + n0 + i4*4+3))*C_DIM + t]) + xv.w;
      tile[t*33 + i4*4+0] = o0;
      tile[t*33 + i4*4+1] = o1;
      tile[t*33 + i4*4+2] = o2;
      tile[t*33 + i4*4+3] = o3;
      ushort4 rv; rv.x=f2b(o0); rv.y=f2b(o1); rv.z=f2b(o2); rv.w=f2b(o3);
      *(ushort4*)&res[xb + i4*4] = rv;
    }
  }
  __syncthreads();
  {
    int n = t & 31, j = t >> 5;
    float s = 0.f, s2 = 0.f;
    #pragma unroll 8
    for (int i = 0; i < 32; ++i) {
      float v = tile[(j*32+i)*33 + n];
      s += v; s2 += v*v;
    }
    psum[j*32+n] = s; psq[j*32+n] = s2;
  }
  __syncthreads();
  if (t < 32) {
    float s=0.f, s2=0.f;
    for (int j=0;j<8;++j){ s += psum[j*32+t]; s2 += psq[j*32+t]; }
    float m = s * (1.f/256.f);
    float var = s2 * (1.f/256.f) - m*m;
    rmean[t] = m; rstd[t] = rsqrtf(var + LN_EPSF);
  }
  __syncthreads();
  int nl = t & 31, cr = t >> 5;
  #pragma unroll 4
  for (int i = 0; i < 32; ++i) {
    int c = i*8 + cr;
    float v = tile[c*33 + nl];
    yt[((size_t)(b*C_DIM + c))*N_DIM + n0 + nl] = f2b((v - rmean[nl]) * rstd[nl] * g[c] + bta[c]);
  }
}

// ---------------- K7: depthwise 3x3 + SiLU gate, bf16 in -> bf16 h (B,128,N)
__global__ __launch_bounds__(256) void k_dwconv(const u16* __restrict__ yt,
     const float* __restrict__ dww, const float* __restrict__ dwb,
     u16* __restrict__ hb) {
  int t = threadIdx.x;
  int blk = blockIdx.x;        // b*8192 + c*64 + ht
  int ht = blk & 63; int c = (blk >> 6) & 127; int b = blk >> 13;
  int hh = t >> 7; int ww = t & 127;
  int h = ht*2 + hh;
  const u16* p1 = yt + ((size_t)(b*256 + c))*N_DIM;
  const u16* p2 = yt + ((size_t)(b*256 + c + 128))*N_DIM;
  float w1[9], w2[9];
  #pragma unroll
  for (int i=0;i<9;++i){ w1[i]=dww[c*9+i]; w2[i]=dww[(c+128)*9+i]; }
  float a1 = dwb[c], a2 = dwb[c+128];
  #pragma unroll
  for (int ky=0;ky<3;++ky){
    int yy = h + ky - 1;
    if (yy < 0 || yy >= H_DIM) continue;
    #pragma unroll
    for (int kx=0;kx<3;++kx){
      int xx = ww + kx - 1;
      if (xx < 0 || xx >= W_DIM) continue;
      float v1 = b2f(p1[yy*W_DIM+xx]), v2 = b2f(p2[yy*W_DIM+xx]);
      a1 += w1[ky*3+kx]*v1; a2 += w2[ky*3+kx]*v2;
    }
  }
  float sig = 1.f/(1.f+expf(-a1));
  hb[((size_t)(b*128+c))*N_DIM + h*W_DIM + ww] = f2b(a1*sig*a2);
}

// ---------------- K8: d_out = pr_w @ h + pr_b + res(bf16)   (bf16 MFMA, pure write)
__global__ __launch_bounds__(256) void k_prfinal_mfma(const u16* __restrict__ hsrc, // (B,128,N) bf16
     const u16* __restrict__ pw,   // (256,128) bf16
     const float* __restrict__ prb,
     const u16* __restrict__ resb, // (B,256,N) bf16
     float* __restrict__ dout) {   // (B,256,N) f32
  __shared__ u16 hls[64*128];      // [n][k], k XOR-swizzled by ((n&7)<<3)
  int t = threadIdx.x;
  int lane = t & 63, w = t >> 6;
  int b = blockIdx.y;
  int n0 = blockIdx.x * 64;
  #pragma unroll
  for (int r = 0; r < 4; ++r) {
    int e = t + 256*r;      // 1024 ushort8 chunks: 128 k x 8 n-chunks
    int k = e >> 3;         // 0..127
    int n8 = (e & 7) * 8;   // 0..56
    short8v v = *(const short8v*)&hsrc[((size_t)(b*128 + k))*N_DIM + n0 + n8];
    #pragma unroll
    for (int j = 0; j < 8; ++j) {
      int n = n8 + j;
      hls[n*128 + (k ^ ((n & 7) << 3))] = (u16)v[j];
    }
  }
  __syncthreads();
  int l15 = lane & 15, lk = (lane >> 4) * 8;
  f32x4 acc[4][4] = {};   // [oi][nj]
  #pragma unroll
  for (int k0 = 0; k0 < 128; k0 += 32) {
    short8v af[4], bf[4];
    #pragma unroll
    for (int oi = 0; oi < 4; ++oi)
      af[oi] = *(const short8v*)&pw[(size_t)(w*64 + oi*16 + l15)*128 + k0 + lk];
    #pragma unroll
    for (int nj = 0; nj < 4; ++nj) {
      int n = nj*16 + l15;
      bf[nj] = *(const short8v*)&hls[n*128 + ((k0 + lk) ^ ((n & 7) << 3))];
    }
    #pragma unroll
    for (int oi = 0; oi < 4; ++oi)
      #pragma unroll
      for (int nj = 0; nj < 4; ++nj)
        acc[oi][nj] = __builtin_amdgcn_mfma_f32_16x16x32_bf16(af[oi], bf[nj], acc[oi][nj], 0,0,0);
  }
  int rbase = (lane >> 4) * 4;
  #pragma unroll
  for (int oi = 0; oi < 4; ++oi)
    #pragma unroll
    for (int r = 0; r < 4; ++r) {
      int o = w*64 + oi*16 + rbase + r;
      float pb = prb[o];
      #pragma unroll
      for (int nj = 0; nj < 4; ++nj) {
        int n = n0 + nj*16 + l15;
        size_t idx = ((size_t)(b*256 + o))*N_DIM + n;
        dout[idx] = acc[oi][nj][r] + pb + b2f(resb[idx]);
      }
    }
}

extern "C" void kernel_launch(void* const* d_in, const int* in_sizes, int n_in,
                              void* d_out, int out_size, void* d_ws, size_t ws_size,
                              hipStream_t stream) {
  const float* x      = (const float*)d_in[0];
  const float* norm_g = (const float*)d_in[1];
  const float* norm_b = (const float*)d_in[2];
  const float* ffn_g  = (const float*)d_in[3];
  const float* ffn_b  = (const float*)d_in[4];
  const float* W_val  = (const float*)d_in[5];
  const float* b_val  = (const float*)d_in[6];
  const float* W_off  = (const float*)d_in[7];
  const float* b_off  = (const float*)d_in[8];
  const float* W_attn = (const float*)d_in[9];
  const float* b_attn = (const float*)d_in[10];
  const float* W_out  = (const float*)d_in[11];
  const float* b_out  = (const float*)d_in[12];
  const float* dw_w   = (const float*)d_in[13];
  const float* dw_b   = (const float*)d_in[14];
  const float* pr_w   = (const float*)d_in[15];
  const float* pr_b   = (const float*)d_in[16];
  float* outp = (float*)d_out;

  char* ws = (char*)d_ws;
  const size_t MB = 1u << 20;
  // layout:
  //  0MB: qbf (16) -> attnbf (16) -> hbuf (8.4)
  // 16MB: valbf (16) -> ytbf (16)
  // 32MB: aobf (16)
  // 48MB: resbf (16)
  // 64MB: boffb f32 (4.2); 69MB: bawb f32 (2.1); 72MB: weights bf16
  u16*   qbf    = (u16*)(ws);
  u16*   attnbf = (u16*)(ws);
  u16*   hbuf   = (u16*)(ws);
  u16*   valbf  = (u16*)(ws + 16*MB);
  u16*   ytbf   = (u16*)(ws + 16*MB);
  u16*   aobf   = (u16*)(ws + 32*MB);
  u16*   resbf  = (u16*)(ws + 48*MB);
  float* boffb  = (float*)(ws + 64*MB);
  float* bawb   = (float*)(ws + 69*MB);
  u16*   wvbf   = (u16*)(ws + 72*MB);
  u16*   wobf   = (u16*)(ws + 72*MB + 131072u);
  u16*   pwbf   = (u16*)(ws + 72*MB + 262144u);
  u16*   wabbf  = (u16*)(ws + 72*MB + 327680u);

  // weights -> bf16 (one launch)
  k_cvt5<<<dim3(172), dim3(256), 0, stream>>>(W_val, W_out, pr_w, W_off, W_attn,
                                              wvbf, wobf, pwbf, wabbf);
  // 1. LN1: x -> q bf16
  k_ln1<<<dim3(1024), dim3(256), 0, stream>>>(x, norm_g, norm_b, qbf);
  // 2. value = q @ W_val^T + b_val (bf16)
  k_gemm_val_mfma<<<dim3(512), dim3(256), 0, stream>>>(qbf, wvbf, b_val, valbf);
  // 3. off / aw via MFMA
  k_offattn_mfma<<<dim3(512), dim3(256), 0, stream>>>(qbf, wabbf, b_off, b_attn, boffb, bawb);
  // 4. deformable sampling -> attn_out bf16 (qbf dead)
  k_sample<<<dim3(8192), dim3(256), 0, stream>>>(valbf, boffb, bawb, attnbf);
  // 5. ao = attn_out @ W_out^T + b_out (bf16, (B,N,C))
  k_gemm_out_mfma<<<dim3(512), dim3(256), 0, stream>>>(attnbf, wobf, b_out, aobf);
  // 6. out = ao + x; LN -> yt bf16 (B,C,N); res bf16
  k_ln2res<<<dim3(1024), dim3(256), 0, stream>>>(aobf, x, ffn_g, ffn_b, ytbf, resbf);
  // 7. depthwise conv + SiLU gate: yt -> h bf16 (attnbf dead)
  k_dwconv<<<dim3(16384), dim3(256), 0, stream>>>(ytbf, dw_w, dw_b, hbuf);
  // 8. d_out = pr_w @ h + pr_b + res
  k_prfinal_mfma<<<dim3(256, 2), dim3(256), 0, stream>>>(hbuf, pwbf, pr_b, resbf, outp);

  (void)in_sizes; (void)n_in; (void)out_size; (void)ws_size;
}